// Round 1
// baseline (396.375 us; speedup 1.0000x reference)
//
#include <hip/hip_runtime.h>

namespace {
constexpr int kB = 4;
constexpr int kS = 2048;
constexpr int kD = 512;
constexpr int kH = 8;
constexpr int kDepth = 64;
constexpr int kNT = kB * kS;  // 8192 tokens
constexpr int kBand = 16;     // keys in [q-16, q+16]
}  // namespace

// ---------------------------------------------------------------------------
// QKV projection: C = A @ W + bias, written head-major [B,H,S,DEPTH].
// grid (kD/64, kNT/64, 3), block 256. z = 0/1/2 -> q/k/v.
// 64x64 tile, BK=16, 4x4 microtile per thread, A-tile transposed in LDS so
// compute reads are float4 (ds_read_b128).
// ---------------------------------------------------------------------------
__global__ __launch_bounds__(256) void qkv_proj_kernel(
    const float* __restrict__ q, const float* __restrict__ k,
    const float* __restrict__ v, const float* __restrict__ wq,
    const float* __restrict__ wk, const float* __restrict__ wv,
    const float* __restrict__ bq, const float* __restrict__ bk,
    const float* __restrict__ bv, float* __restrict__ Qh,
    float* __restrict__ Kh, float* __restrict__ Vh) {
  const float* A;
  const float* W;
  const float* bias;
  float* C;
  switch (blockIdx.z) {
    case 0: A = q; W = wq; bias = bq; C = Qh; break;
    case 1: A = k; W = wk; bias = bk; C = Kh; break;
    default: A = v; W = wv; bias = bv; C = Vh; break;
  }

  __shared__ alignas(16) float As[16][68];  // [k][m]; 68 keeps 16B align + bank spread
  __shared__ alignas(16) float Ws[16][64];  // [k][n]

  const int tid = threadIdx.x;
  const int tx = tid & 15;
  const int ty = tid >> 4;
  const int row0 = blockIdx.y * 64;
  const int col0 = blockIdx.x * 64;

  // loader mapping
  const int am = tid >> 2;          // 0..63 A row
  const int ak = (tid & 3) << 2;    // 0,4,8,12 A k-offset
  const int wr = tid >> 4;          // 0..15 W k-row
  const int wc = (tid & 15) << 2;   // 0..60 W col

  float acc[4][4];
#pragma unroll
  for (int i = 0; i < 4; ++i)
#pragma unroll
    for (int j = 0; j < 4; ++j) acc[i][j] = 0.f;

  for (int k0 = 0; k0 < kD; k0 += 16) {
    const float4 a4 =
        *(const float4*)(A + (size_t)(row0 + am) * kD + (k0 + ak));
    As[ak + 0][am] = a4.x;
    As[ak + 1][am] = a4.y;
    As[ak + 2][am] = a4.z;
    As[ak + 3][am] = a4.w;
    *(float4*)(&Ws[wr][wc]) =
        *(const float4*)(W + (size_t)(k0 + wr) * kD + (col0 + wc));
    __syncthreads();
#pragma unroll
    for (int kk = 0; kk < 16; ++kk) {
      const float4 av = *(const float4*)(&As[kk][ty * 4]);
      const float4 wv4 = *(const float4*)(&Ws[kk][tx * 4]);
      const float a[4] = {av.x, av.y, av.z, av.w};
      const float w[4] = {wv4.x, wv4.y, wv4.z, wv4.w};
#pragma unroll
      for (int i = 0; i < 4; ++i)
#pragma unroll
        for (int j = 0; j < 4; ++j) acc[i][j] += a[i] * w[j];
    }
    __syncthreads();
  }

  // epilogue: col tile is exactly one head (64 wide), write head-major
  const int h = col0 >> 6;
  const float4 b4 = *(const float4*)(bias + col0 + tx * 4);
#pragma unroll
  for (int i = 0; i < 4; ++i) {
    const int token = row0 + ty * 4 + i;
    const int bb = token >> 11;         // / kS
    const int ss = token & (kS - 1);
    float* dst = C + ((((size_t)bb * kH + h) * kS + ss) << 6) + tx * 4;
    *(float4*)dst = make_float4(acc[i][0] + b4.x, acc[i][1] + b4.y,
                                acc[i][2] + b4.z, acc[i][3] + b4.w);
  }
}

// ---------------------------------------------------------------------------
// Banded attention, one wave per 64-query tile per (b,h).
// grid (kS/64, kB*kH), block 64. O may alias Qh: each block reads only its
// own Q rows (into registers) before writing the same rows as output.
// ---------------------------------------------------------------------------
__global__ __launch_bounds__(64) void band_attn_kernel(
    const float* __restrict__ Qh, const float* __restrict__ Kh,
    const float* __restrict__ Vh, float* __restrict__ O) {
  __shared__ alignas(16) float Kt[96][65];
  __shared__ alignas(16) float Vt[96][65];
  __shared__ alignas(16) float Lt[64][34];

  const int tid = threadIdx.x;
  const int bh = blockIdx.y;
  const int qs = blockIdx.x * 64;
  const float* Kb = Kh + ((size_t)bh * kS) * kDepth;
  const float* Vb = Vh + ((size_t)bh * kS) * kDepth;

  // stage K/V rows qs-16 .. qs+79 (zeros outside [0,S))
#pragma unroll
  for (int it = 0; it < 24; ++it) {
    const int idx4 = it * 64 + tid;   // float4 index within 96x64 tile
    const int r = idx4 >> 4;
    const int c = (idx4 & 15) << 2;
    const int g = qs - kBand + r;
    float4 xk = make_float4(0.f, 0.f, 0.f, 0.f);
    float4 xv = make_float4(0.f, 0.f, 0.f, 0.f);
    if (g >= 0 && g < kS) {
      xk = *(const float4*)(Kb + ((size_t)g << 6) + c);
      xv = *(const float4*)(Vb + ((size_t)g << 6) + c);
    }
    Kt[r][c] = xk.x; Kt[r][c + 1] = xk.y; Kt[r][c + 2] = xk.z; Kt[r][c + 3] = xk.w;
    Vt[r][c] = xv.x; Vt[r][c + 1] = xv.y; Vt[r][c + 2] = xv.z; Vt[r][c + 3] = xv.w;
  }

  // per-thread query row into registers
  const int qg = qs + tid;
  const float* Qrow = Qh + (((size_t)bh * kS + qg) << 6);
  float qreg[64];
#pragma unroll
  for (int d4 = 0; d4 < 16; ++d4) {
    const float4 x = *(const float4*)(Qrow + d4 * 4);
    qreg[d4 * 4 + 0] = x.x;
    qreg[d4 * 4 + 1] = x.y;
    qreg[d4 * 4 + 2] = x.z;
    qreg[d4 * 4 + 3] = x.w;
  }
  __syncthreads();

  // logits (scale = 1/sqrt(64) = 0.125), masked keys -> -3e38 -> exp -> 0
  float mx = -3.0e38f;
  for (int jj = 0; jj < 33; ++jj) {
    const int j = qg - kBand + jj;
    float logit = -3.0e38f;
    if (j >= 0 && j < kS) {
      float accl = 0.f;
#pragma unroll
      for (int d = 0; d < 64; ++d) accl += qreg[d] * Kt[tid + jj][d];
      logit = accl * 0.125f;
    }
    Lt[tid][jj] = logit;
    mx = fmaxf(mx, logit);
  }

  float p[33];
  float sum = 0.f;
#pragma unroll
  for (int jj = 0; jj < 33; ++jj) {
    const float e = __expf(Lt[tid][jj] - mx);
    p[jj] = e;
    sum += e;
  }
  const float inv = 1.f / sum;

  float outd[64];
#pragma unroll
  for (int d = 0; d < 64; ++d) outd[d] = 0.f;
  for (int jj = 0; jj < 33; ++jj) {
    const float pj = p[jj];
#pragma unroll
    for (int d = 0; d < 64; ++d) outd[d] += pj * Vt[tid + jj][d];
  }

  float* Ob = O + (((size_t)bh * kS + qg) << 6);
#pragma unroll
  for (int d4 = 0; d4 < 16; ++d4) {
    *(float4*)(Ob + d4 * 4) =
        make_float4(outd[d4 * 4 + 0] * inv, outd[d4 * 4 + 1] * inv,
                    outd[d4 * 4 + 2] * inv, outd[d4 * 4 + 3] * inv);
  }
}

// ---------------------------------------------------------------------------
// Output projection: out[token][n] = sum_k O_headmajor[token][k] * wo[k][n] + bo
// grid (kD/64, kNT/64), block 256. Same tile structure as qkv_proj.
// ---------------------------------------------------------------------------
__global__ __launch_bounds__(256) void out_proj_kernel(
    const float* __restrict__ O, const float* __restrict__ wo,
    const float* __restrict__ bo, float* __restrict__ out) {
  __shared__ alignas(16) float As[16][68];
  __shared__ alignas(16) float Ws[16][64];

  const int tid = threadIdx.x;
  const int tx = tid & 15;
  const int ty = tid >> 4;
  const int row0 = blockIdx.y * 64;
  const int col0 = blockIdx.x * 64;

  const int am = tid >> 2;
  const int ak = (tid & 3) << 2;
  const int wr = tid >> 4;
  const int wc = (tid & 15) << 2;

  const int token = row0 + am;
  const int bb = token >> 11;
  const int ss = token & (kS - 1);

  float acc[4][4];
#pragma unroll
  for (int i = 0; i < 4; ++i)
#pragma unroll
    for (int j = 0; j < 4; ++j) acc[i][j] = 0.f;

  for (int k0 = 0; k0 < kD; k0 += 16) {
    const int kg = k0 + ak;
    const int h = kg >> 6;
    const int dd = kg & 63;
    const float4 a4 =
        *(const float4*)(O + ((((size_t)bb * kH + h) * kS + ss) << 6) + dd);
    As[ak + 0][am] = a4.x;
    As[ak + 1][am] = a4.y;
    As[ak + 2][am] = a4.z;
    As[ak + 3][am] = a4.w;
    *(float4*)(&Ws[wr][wc]) =
        *(const float4*)(wo + (size_t)(k0 + wr) * kD + (col0 + wc));
    __syncthreads();
#pragma unroll
    for (int kk = 0; kk < 16; ++kk) {
      const float4 av = *(const float4*)(&As[kk][ty * 4]);
      const float4 wv4 = *(const float4*)(&Ws[kk][tx * 4]);
      const float a[4] = {av.x, av.y, av.z, av.w};
      const float w[4] = {wv4.x, wv4.y, wv4.z, wv4.w};
#pragma unroll
      for (int i = 0; i < 4; ++i)
#pragma unroll
        for (int j = 0; j < 4; ++j) acc[i][j] += a[i] * w[j];
    }
    __syncthreads();
  }

  const float4 b4 = *(const float4*)(bo + col0 + tx * 4);
#pragma unroll
  for (int i = 0; i < 4; ++i) {
    const int tok = row0 + ty * 4 + i;
    float* dst = out + (size_t)tok * kD + col0 + tx * 4;
    *(float4*)dst = make_float4(acc[i][0] + b4.x, acc[i][1] + b4.y,
                                acc[i][2] + b4.z, acc[i][3] + b4.w);
  }
}

extern "C" void kernel_launch(void* const* d_in, const int* in_sizes, int n_in,
                              void* d_out, int out_size, void* d_ws,
                              size_t ws_size, hipStream_t stream) {
  const float* q = (const float*)d_in[0];
  const float* k = (const float*)d_in[1];
  const float* v = (const float*)d_in[2];
  const float* wq = (const float*)d_in[3];
  const float* bq = (const float*)d_in[4];
  const float* wk = (const float*)d_in[5];
  const float* bk = (const float*)d_in[6];
  const float* wv = (const float*)d_in[7];
  const float* bv = (const float*)d_in[8];
  const float* wo = (const float*)d_in[9];
  const float* bo = (const float*)d_in[10];
  float* out = (float*)d_out;

  // workspace: Qh | Kh | Vh  (each kNT*kD floats, head-major [B,H,S,64]).
  // Attention output O aliases Qh (safe: each attn block reads only its own
  // Q rows, into registers, before writing those same rows).
  float* Qh = (float*)d_ws;
  float* Kh = Qh + (size_t)kNT * kD;
  float* Vh = Kh + (size_t)kNT * kD;
  float* O = Qh;

  qkv_proj_kernel<<<dim3(kD / 64, kNT / 64, 3), 256, 0, stream>>>(
      q, k, v, wq, wk, wv, bq, bk, bv, Qh, Kh, Vh);
  band_attn_kernel<<<dim3(kS / 64, kB * kH), 64, 0, stream>>>(Qh, Kh, Vh, O);
  out_proj_kernel<<<dim3(kD / 64, kNT / 64), 256, 0, stream>>>(O, wo, bo, out);
}

// Round 3
// 205.638 us; speedup vs baseline: 1.9275x; 1.9275x over previous
//
#include <hip/hip_runtime.h>

typedef unsigned int uint;
typedef unsigned short ushort;
typedef __attribute__((ext_vector_type(8))) short bf16x8;
typedef __attribute__((ext_vector_type(4))) float f32x4;

namespace {
constexpr int kB = 4;
constexpr int kS = 2048;
constexpr int kD = 512;
constexpr int kH = 8;
constexpr int kNT = kB * kS;  // 8192 tokens
constexpr int kBand = 16;
}  // namespace

static __device__ __forceinline__ ushort f2bf(float f) {
  uint u = __builtin_bit_cast(uint, f);
  u = (u + 0x7fffu + ((u >> 16) & 1u)) >> 16;  // RNE
  return (ushort)u;
}
static __device__ __forceinline__ float bf_lo(uint w) {
  return __builtin_bit_cast(float, w << 16);
}
static __device__ __forceinline__ float bf_hi(uint w) {
  return __builtin_bit_cast(float, w & 0xffff0000u);
}

// ---------------------------------------------------------------------------
// Weight prep: WT[z][n][k] = bf16(W[z][k][n]), z in {wq,wk,wv,wo}.
// grid (8,8,4): 64x64 tiles over 512x512. block 256.
// ---------------------------------------------------------------------------
__global__ __launch_bounds__(256) void prep_w_kernel(
    const float* __restrict__ wq, const float* __restrict__ wk,
    const float* __restrict__ wv, const float* __restrict__ wo,
    ushort* __restrict__ WT) {
  const float* W;
  switch (blockIdx.z) {
    case 0: W = wq; break;
    case 1: W = wk; break;
    case 2: W = wv; break;
    default: W = wo; break;
  }
  ushort* T = WT + (size_t)blockIdx.z * kD * kD;
  __shared__ float Ws[64][65];
  const int tid = threadIdx.x;
  const int kt = blockIdx.x * 64, nt = blockIdx.y * 64;
  const int r = tid >> 2, c0 = (tid & 3) * 16;
#pragma unroll
  for (int i = 0; i < 4; ++i) {
    const float4 x = *(const float4*)(W + (size_t)(kt + r) * kD + nt + c0 + i * 4);
    Ws[r][c0 + i * 4 + 0] = x.x;
    Ws[r][c0 + i * 4 + 1] = x.y;
    Ws[r][c0 + i * 4 + 2] = x.z;
    Ws[r][c0 + i * 4 + 3] = x.w;
  }
  __syncthreads();
  const int n = tid >> 2, k0 = (tid & 3) * 16;
  alignas(16) ushort tmp[16];
#pragma unroll
  for (int i = 0; i < 16; ++i) tmp[i] = f2bf(Ws[k0 + i][n]);
  ushort* dst = T + (size_t)(nt + n) * kD + kt + k0;
  *(uint4*)(dst + 0) = *(const uint4*)&tmp[0];
  *(uint4*)(dst + 8) = *(const uint4*)&tmp[8];
}

// ---------------------------------------------------------------------------
// QKV projection, bf16 MFMA. C = A @ W + bias, head-major out.
// z=0 -> Qh (fp32), z=1 -> Khb (bf16), z=2 -> Vhb (bf16).
// grid (4, 64, 3), block 256 (4 waves, 2x2 of 64x64 per wave).
// Tile 128x128, BK=32. LDS chunk-major: [k-octet][row][8 bf16].
// ---------------------------------------------------------------------------
__global__ __launch_bounds__(256) void qkv_gemm_kernel(
    const float* __restrict__ q, const float* __restrict__ k,
    const float* __restrict__ v, const ushort* __restrict__ WT,
    const float* __restrict__ bq, const float* __restrict__ bk,
    const float* __restrict__ bv, float* __restrict__ Qh,
    ushort* __restrict__ Khb, ushort* __restrict__ Vhb) {
  const float* A;
  const float* bias;
  switch (blockIdx.z) {
    case 0: A = q; bias = bq; break;
    case 1: A = k; bias = bk; break;
    default: A = v; bias = bv; break;
  }
  const ushort* BT = WT + (size_t)blockIdx.z * kD * kD;

  __shared__ alignas(16) short Asm[4][128][8];
  __shared__ alignas(16) short Bsm[4][128][8];

  const int tid = threadIdx.x;
  const int wave = tid >> 6, lane = tid & 63, l15 = lane & 15, qd = lane >> 4;
  const int wm = (wave >> 1) * 64, wn = (wave & 1) * 64;
  const int row0 = blockIdx.y * 128, col0 = blockIdx.x * 128;
  const int sm = tid >> 1, sh = tid & 1;

  f32x4 acc[4][4];
#pragma unroll
  for (int mi = 0; mi < 4; ++mi)
#pragma unroll
    for (int ni = 0; ni < 4; ++ni) acc[mi][ni] = (f32x4)(0.f);

  for (int k0 = 0; k0 < kD; k0 += 32) {
    // stage A (fp32 -> bf16), 16 elems/thread
    const float* ap = A + (size_t)(row0 + sm) * kD + k0 + sh * 16;
    const float4 a0 = *(const float4*)(ap + 0);
    const float4 a1 = *(const float4*)(ap + 4);
    const float4 a2 = *(const float4*)(ap + 8);
    const float4 a3 = *(const float4*)(ap + 12);
    alignas(16) ushort t16[16] = {
        f2bf(a0.x), f2bf(a0.y), f2bf(a0.z), f2bf(a0.w),
        f2bf(a1.x), f2bf(a1.y), f2bf(a1.z), f2bf(a1.w),
        f2bf(a2.x), f2bf(a2.y), f2bf(a2.z), f2bf(a2.w),
        f2bf(a3.x), f2bf(a3.y), f2bf(a3.z), f2bf(a3.w)};
    *(uint4*)&Asm[sh * 2 + 0][sm][0] = *(const uint4*)&t16[0];
    *(uint4*)&Asm[sh * 2 + 1][sm][0] = *(const uint4*)&t16[8];
    // stage B (already bf16), 16 elems/thread
    const ushort* bp = BT + (size_t)(col0 + sm) * kD + k0 + sh * 16;
    *(uint4*)&Bsm[sh * 2 + 0][sm][0] = *(const uint4*)(bp + 0);
    *(uint4*)&Bsm[sh * 2 + 1][sm][0] = *(const uint4*)(bp + 8);
    __syncthreads();

    bf16x8 af[4], br[4];
#pragma unroll
    for (int mi = 0; mi < 4; ++mi)
      af[mi] = *(const bf16x8*)&Asm[qd][wm + mi * 16 + l15][0];
#pragma unroll
    for (int ni = 0; ni < 4; ++ni)
      br[ni] = *(const bf16x8*)&Bsm[qd][wn + ni * 16 + l15][0];
#pragma unroll
    for (int mi = 0; mi < 4; ++mi)
#pragma unroll
      for (int ni = 0; ni < 4; ++ni)
        acc[mi][ni] = __builtin_amdgcn_mfma_f32_16x16x32_bf16(
            af[mi], br[ni], acc[mi][ni], 0, 0, 0);
    __syncthreads();
  }

  float bcol[4];
#pragma unroll
  for (int ni = 0; ni < 4; ++ni) bcol[ni] = bias[col0 + wn + ni * 16 + l15];

  const int z = blockIdx.z;
#pragma unroll
  for (int mi = 0; mi < 4; ++mi) {
#pragma unroll
    for (int ni = 0; ni < 4; ++ni) {
      const int n_g = col0 + wn + ni * 16 + l15;
      const int h = n_g >> 6, d = n_g & 63;
#pragma unroll
      for (int r = 0; r < 4; ++r) {
        const int token = row0 + wm + mi * 16 + qd * 4 + r;
        const int bb = token >> 11, ss = token & (kS - 1);
        const size_t off = ((((size_t)bb * kH + h) * kS + ss) << 6) + d;
        const float val = acc[mi][ni][r] + bcol[ni];
        if (z == 0) Qh[off] = val;
        else if (z == 1) Khb[off] = f2bf(val);
        else Vhb[off] = f2bf(val);
      }
    }
  }
}

// ---------------------------------------------------------------------------
// Banded attention: Q fp32, K/V bf16 in LDS. One wave per 64-query tile.
// grid (32, 32), block 64. O (fp32, head-major) aliases Qh.
// ---------------------------------------------------------------------------
__global__ __launch_bounds__(64) void band_attn_kernel(
    const float* __restrict__ Qh, const ushort* __restrict__ Khb,
    const ushort* __restrict__ Vhb, float* __restrict__ O) {
  __shared__ alignas(16) ushort Kt[96][72];  // +8 pad: row stride 144B
  __shared__ alignas(16) ushort Vt[96][72];
  __shared__ float Lp[64][34];

  const int tid = threadIdx.x;
  const int bh = blockIdx.y;
  const int qs = blockIdx.x * 64;

  // stage K/V rows qs-16 .. qs+79 as bf16
#pragma unroll
  for (int it = 0; it < 12; ++it) {
    const int idx = it * 64 + tid;       // uint4 index in 96x(64/8)
    const int r = idx >> 3;
    const int c8 = (idx & 7) * 8;
    const int g = qs - kBand + r;
    uint4 xk = make_uint4(0, 0, 0, 0), xv = make_uint4(0, 0, 0, 0);
    if (g >= 0 && g < kS) {
      const size_t base = (((size_t)bh * kS + g) << 6) + c8;
      xk = *(const uint4*)(Khb + base);
      xv = *(const uint4*)(Vhb + base);
    }
    *(uint4*)&Kt[r][c8] = xk;
    *(uint4*)&Vt[r][c8] = xv;
  }

  const int qg = qs + tid;
  const float* Qrow = Qh + (((size_t)bh * kS + qg) << 6);
  float qreg[64];
#pragma unroll
  for (int d4 = 0; d4 < 16; ++d4) {
    const float4 x = *(const float4*)(Qrow + d4 * 4);
    qreg[d4 * 4 + 0] = x.x;
    qreg[d4 * 4 + 1] = x.y;
    qreg[d4 * 4 + 2] = x.z;
    qreg[d4 * 4 + 3] = x.w;
  }
  __syncthreads();

  // pass 1: logits
  float mx = -3.0e38f;
#pragma unroll 1
  for (int jj = 0; jj < 33; ++jj) {
    const int j = qg - kBand + jj;
    float logit = -3.0e38f;
    if (j >= 0 && j < kS) {
      const uint4* kr = (const uint4*)&Kt[tid + jj][0];
      float accl = 0.f;
#pragma unroll
      for (int c = 0; c < 8; ++c) {
        const uint4 u = kr[c];
        const int e = c * 8;
        accl += qreg[e + 0] * bf_lo(u.x) + qreg[e + 1] * bf_hi(u.x);
        accl += qreg[e + 2] * bf_lo(u.y) + qreg[e + 3] * bf_hi(u.y);
        accl += qreg[e + 4] * bf_lo(u.z) + qreg[e + 5] * bf_hi(u.z);
        accl += qreg[e + 6] * bf_lo(u.w) + qreg[e + 7] * bf_hi(u.w);
      }
      logit = accl * 0.125f;
    }
    Lp[tid][jj] = logit;
    mx = fmaxf(mx, logit);
  }

  // pass 2: exp + sum (store p back into Lp)
  float sum = 0.f;
#pragma unroll 1
  for (int jj = 0; jj < 33; ++jj) {
    const float e = __expf(Lp[tid][jj] - mx);
    sum += e;
    Lp[tid][jj] = e;
  }
  const float inv = 1.f / sum;

  // pass 3: PV
  float outd[64];
#pragma unroll
  for (int d = 0; d < 64; ++d) outd[d] = 0.f;
#pragma unroll 1
  for (int jj = 0; jj < 33; ++jj) {
    const float pj = Lp[tid][jj];
    const uint4* vr = (const uint4*)&Vt[tid + jj][0];
#pragma unroll
    for (int c = 0; c < 8; ++c) {
      const uint4 u = vr[c];
      const int e = c * 8;
      outd[e + 0] += pj * bf_lo(u.x);
      outd[e + 1] += pj * bf_hi(u.x);
      outd[e + 2] += pj * bf_lo(u.y);
      outd[e + 3] += pj * bf_hi(u.y);
      outd[e + 4] += pj * bf_lo(u.z);
      outd[e + 5] += pj * bf_hi(u.z);
      outd[e + 6] += pj * bf_lo(u.w);
      outd[e + 7] += pj * bf_hi(u.w);
    }
  }

  float* Ob = O + (((size_t)bh * kS + qg) << 6);
#pragma unroll
  for (int d4 = 0; d4 < 16; ++d4) {
    *(float4*)(Ob + d4 * 4) =
        make_float4(outd[d4 * 4 + 0] * inv, outd[d4 * 4 + 1] * inv,
                    outd[d4 * 4 + 2] * inv, outd[d4 * 4 + 3] * inv);
  }
}

// ---------------------------------------------------------------------------
// Output projection, bf16 MFMA. A = O (fp32 head-major, converted inline),
// B = WoT bf16. out[token][n] += bo. grid (4, 64), block 256.
// ---------------------------------------------------------------------------
__global__ __launch_bounds__(256) void out_gemm_kernel(
    const float* __restrict__ O, const ushort* __restrict__ WoT,
    const float* __restrict__ bo, float* __restrict__ out) {
  __shared__ alignas(16) short Asm[4][128][8];
  __shared__ alignas(16) short Bsm[4][128][8];

  const int tid = threadIdx.x;
  const int wave = tid >> 6, lane = tid & 63, l15 = lane & 15, qd = lane >> 4;
  const int wm = (wave >> 1) * 64, wn = (wave & 1) * 64;
  const int row0 = blockIdx.y * 128, col0 = blockIdx.x * 128;
  const int sm = tid >> 1, sh = tid & 1;

  const int token_s = row0 + sm;
  const int bb_s = token_s >> 11, ss_s = token_s & (kS - 1);

  f32x4 acc[4][4];
#pragma unroll
  for (int mi = 0; mi < 4; ++mi)
#pragma unroll
    for (int ni = 0; ni < 4; ++ni) acc[mi][ni] = (f32x4)(0.f);

  for (int k0 = 0; k0 < kD; k0 += 32) {
    const int kk = k0 + sh * 16;
    const int h = kk >> 6, dd = kk & 63;
    const float* ap = O + ((((size_t)bb_s * kH + h) * kS + ss_s) << 6) + dd;
    const float4 a0 = *(const float4*)(ap + 0);
    const float4 a1 = *(const float4*)(ap + 4);
    const float4 a2 = *(const float4*)(ap + 8);
    const float4 a3 = *(const float4*)(ap + 12);
    alignas(16) ushort t16[16] = {
        f2bf(a0.x), f2bf(a0.y), f2bf(a0.z), f2bf(a0.w),
        f2bf(a1.x), f2bf(a1.y), f2bf(a1.z), f2bf(a1.w),
        f2bf(a2.x), f2bf(a2.y), f2bf(a2.z), f2bf(a2.w),
        f2bf(a3.x), f2bf(a3.y), f2bf(a3.z), f2bf(a3.w)};
    *(uint4*)&Asm[sh * 2 + 0][sm][0] = *(const uint4*)&t16[0];
    *(uint4*)&Asm[sh * 2 + 1][sm][0] = *(const uint4*)&t16[8];
    const ushort* bp = WoT + (size_t)(col0 + sm) * kD + k0 + sh * 16;
    *(uint4*)&Bsm[sh * 2 + 0][sm][0] = *(const uint4*)(bp + 0);
    *(uint4*)&Bsm[sh * 2 + 1][sm][0] = *(const uint4*)(bp + 8);
    __syncthreads();

    bf16x8 af[4], br[4];
#pragma unroll
    for (int mi = 0; mi < 4; ++mi)
      af[mi] = *(const bf16x8*)&Asm[qd][wm + mi * 16 + l15][0];
#pragma unroll
    for (int ni = 0; ni < 4; ++ni)
      br[ni] = *(const bf16x8*)&Bsm[qd][wn + ni * 16 + l15][0];
#pragma unroll
    for (int mi = 0; mi < 4; ++mi)
#pragma unroll
      for (int ni = 0; ni < 4; ++ni)
        acc[mi][ni] = __builtin_amdgcn_mfma_f32_16x16x32_bf16(
            af[mi], br[ni], acc[mi][ni], 0, 0, 0);
    __syncthreads();
  }

  float bcol[4];
#pragma unroll
  for (int ni = 0; ni < 4; ++ni) bcol[ni] = bo[col0 + wn + ni * 16 + l15];

#pragma unroll
  for (int mi = 0; mi < 4; ++mi) {
#pragma unroll
    for (int ni = 0; ni < 4; ++ni) {
      const int n_g = col0 + wn + ni * 16 + l15;
#pragma unroll
      for (int r = 0; r < 4; ++r) {
        const int token = row0 + wm + mi * 16 + qd * 4 + r;
        out[(size_t)token * kD + n_g] = acc[mi][ni][r] + bcol[ni];
      }
    }
  }
}

extern "C" void kernel_launch(void* const* d_in, const int* in_sizes, int n_in,
                              void* d_out, int out_size, void* d_ws,
                              size_t ws_size, hipStream_t stream) {
  const float* q = (const float*)d_in[0];
  const float* k = (const float*)d_in[1];
  const float* v = (const float*)d_in[2];
  const float* wq = (const float*)d_in[3];
  const float* bq = (const float*)d_in[4];
  const float* wk = (const float*)d_in[5];
  const float* bk = (const float*)d_in[6];
  const float* wv = (const float*)d_in[7];
  const float* bv = (const float*)d_in[8];
  const float* wo = (const float*)d_in[9];
  const float* bo = (const float*)d_in[10];
  float* out = (float*)d_out;

  // ws: Qh fp32 (16MB) | Khb bf16 (8MB) | Vhb bf16 (8MB) | WT bf16 x4 (2MB)
  float* Qh = (float*)d_ws;
  ushort* Khb = (ushort*)(Qh + (size_t)kNT * kD);
  ushort* Vhb = Khb + (size_t)kNT * kD;
  ushort* WT = Vhb + (size_t)kNT * kD;
  float* O = Qh;  // alias: attn reads its own Q rows before writing them

  prep_w_kernel<<<dim3(8, 8, 4), 256, 0, stream>>>(wq, wk, wv, wo, WT);
  qkv_gemm_kernel<<<dim3(4, 64, 3), 256, 0, stream>>>(q, k, v, WT, bq, bk, bv,
                                                      Qh, Khb, Vhb);
  band_attn_kernel<<<dim3(kS / 64, kB * kH), 64, 0, stream>>>(Qh, Khb, Vhb, O);
  out_gemm_kernel<<<dim3(4, 64), 256, 0, stream>>>(O, WT + (size_t)3 * kD * kD,
                                                   bo, out);
}

// Round 4
// 180.897 us; speedup vs baseline: 2.1912x; 1.1368x over previous
//
#include <hip/hip_runtime.h>

typedef unsigned int uint;
typedef unsigned short ushort;
typedef __attribute__((ext_vector_type(8))) short bf16x8;
typedef __attribute__((ext_vector_type(4))) float f32x4;

namespace {
constexpr int kS = 2048;
constexpr int kD = 512;
constexpr int kH = 8;
constexpr int kNT = 8192;  // B*S
constexpr int kBand = 16;
}  // namespace

static __device__ __forceinline__ ushort f2bf(float f) {
  uint u = __builtin_bit_cast(uint, f);
  u = (u + 0x7fffu + ((u >> 16) & 1u)) >> 16;  // RNE
  return (ushort)u;
}

// global -> LDS direct DMA, 16B per lane. LDS dest = wave-uniform base + lane*16.
#define GLD16(gp, lp)                                                   \
  __builtin_amdgcn_global_load_lds(                                     \
      (const __attribute__((address_space(1))) uint*)(gp),              \
      (__attribute__((address_space(3))) uint*)(lp), 16, 0, 0)

// ---------------------------------------------------------------------------
// Weight prep: WT[z][n][k] = bf16(W[z][k][n]). grid (8,8,4), block 256.
// ---------------------------------------------------------------------------
__global__ __launch_bounds__(256) void prep_w_kernel(
    const float* __restrict__ wq, const float* __restrict__ wk,
    const float* __restrict__ wv, const float* __restrict__ wo,
    ushort* __restrict__ WT) {
  const float* W;
  switch (blockIdx.z) {
    case 0: W = wq; break;
    case 1: W = wk; break;
    case 2: W = wv; break;
    default: W = wo; break;
  }
  ushort* T = WT + (size_t)blockIdx.z * kD * kD;
  __shared__ float Ws[64][65];
  const int tid = threadIdx.x;
  const int kt = blockIdx.x * 64, nt = blockIdx.y * 64;
  const int r = tid >> 2, c0 = (tid & 3) * 16;
#pragma unroll
  for (int i = 0; i < 4; ++i) {
    const float4 x = *(const float4*)(W + (size_t)(kt + r) * kD + nt + c0 + i * 4);
    Ws[r][c0 + i * 4 + 0] = x.x;
    Ws[r][c0 + i * 4 + 1] = x.y;
    Ws[r][c0 + i * 4 + 2] = x.z;
    Ws[r][c0 + i * 4 + 3] = x.w;
  }
  __syncthreads();
  const int n = tid >> 2, k0 = (tid & 3) * 16;
  alignas(16) ushort tmp[16];
#pragma unroll
  for (int i = 0; i < 16; ++i) tmp[i] = f2bf(Ws[k0 + i][n]);
  ushort* dst = T + (size_t)(nt + n) * kD + kt + k0;
  *(uint4*)(dst + 0) = *(const uint4*)&tmp[0];
  *(uint4*)(dst + 8) = *(const uint4*)&tmp[8];
}

// ---------------------------------------------------------------------------
// Activation prep: q,k fp32 -> bf16 row-major. grid (2048, 2), block 256.
// ---------------------------------------------------------------------------
__global__ __launch_bounds__(256) void prep_act_kernel(
    const float* __restrict__ q, const float* __restrict__ k,
    ushort* __restrict__ qb, ushort* __restrict__ kb) {
  const float* src = blockIdx.y ? k : q;
  ushort* dst = blockIdx.y ? kb : qb;
  const size_t i8 = ((size_t)blockIdx.x * 256 + threadIdx.x) * 8;
  const float4 x0 = *(const float4*)(src + i8);
  const float4 x1 = *(const float4*)(src + i8 + 4);
  alignas(16) ushort t8[8] = {f2bf(x0.x), f2bf(x0.y), f2bf(x0.z), f2bf(x0.w),
                              f2bf(x1.x), f2bf(x1.y), f2bf(x1.z), f2bf(x1.w)};
  *(uint4*)(dst + i8) = *(const uint4*)t8;
}

// ---------------------------------------------------------------------------
// Unified 128x128 BK=32 bf16 MFMA GEMM, global_load_lds staging + XOR swizzle.
// mode = mode_arg + blockIdx.z:
//   0: qb @ WTq + bq -> Qp  (bf16 [tok][512])
//   1: kb @ WTk + bk -> Kp  (bf16 [tok][512])
//   2: v(fp32, inline cvt) @ WTv + bv -> VT (bf16 [bh][64][2048], transposed)
//   3: Ob @ WTo + bo -> out (fp32 [tok][512])
// ---------------------------------------------------------------------------
__global__ __launch_bounds__(256) void gemm_kernel(
    const ushort* __restrict__ qb, const ushort* __restrict__ kb,
    const float* __restrict__ vf, const ushort* __restrict__ obp,
    const ushort* __restrict__ WT, const float* __restrict__ bq,
    const float* __restrict__ bk, const float* __restrict__ bv,
    const float* __restrict__ bo, ushort* __restrict__ Qp,
    ushort* __restrict__ Kp, ushort* __restrict__ VT,
    float* __restrict__ outp, int mode_arg) {
  const int mode = mode_arg + blockIdx.z;
  const ushort* Ab = nullptr;
  const float* Af = nullptr;
  const float* bias;
  switch (mode) {
    case 0: Ab = qb; bias = bq; break;
    case 1: Ab = kb; bias = bk; break;
    case 2: Af = vf; bias = bv; break;
    default: Ab = obp; bias = bo; break;
  }
  const ushort* BT = WT + (size_t)mode * kD * kD;

  // row-major tiles, 32 bf16 (4 x 16B chunks) per row, NO padding
  // (global_load_lds requires it); chunk c of row r holds global chunk c^s(r).
  __shared__ alignas(16) ushort Asm[128 * 32];
  __shared__ alignas(16) ushort Bsm[128 * 32];

  const int tid = threadIdx.x;
  const int wave = tid >> 6, lane = tid & 63, l15 = lane & 15, qd = lane >> 4;
  const int wm = (wave >> 1) * 64, wn = (wave & 1) * 64;
  const int row0 = blockIdx.y * 128, col0 = blockIdx.x * 128;
  const int sw = (l15 & 3) ^ (l15 >> 2);  // = s(row) for all frag rows

  // loader mapping (2 issues of 256 lanes x 16B)
  int lr[2], lg[2];
#pragma unroll
  for (int i = 0; i < 2; ++i) {
    const int linear = i * 256 + tid;
    lr[i] = linear >> 2;
    const int c = linear & 3;
    lg[i] = c ^ ((lr[i] & 3) ^ ((lr[i] >> 2) & 3));
  }

  f32x4 acc[4][4];
#pragma unroll
  for (int mi = 0; mi < 4; ++mi)
#pragma unroll
    for (int ni = 0; ni < 4; ++ni) acc[mi][ni] = (f32x4)(0.f);

  for (int k0 = 0; k0 < kD; k0 += 32) {
    if (mode == 2) {
#pragma unroll
      for (int i = 0; i < 2; ++i) {
        const float* ap = Af + (size_t)(row0 + lr[i]) * kD + k0 + lg[i] * 8;
        const float4 x0 = *(const float4*)ap;
        const float4 x1 = *(const float4*)(ap + 4);
        alignas(16) ushort t8[8] = {f2bf(x0.x), f2bf(x0.y), f2bf(x0.z),
                                    f2bf(x0.w), f2bf(x1.x), f2bf(x1.y),
                                    f2bf(x1.z), f2bf(x1.w)};
        *(uint4*)&Asm[(i * 256 + tid) * 8] = *(const uint4*)t8;
      }
    } else {
#pragma unroll
      for (int i = 0; i < 2; ++i)
        GLD16(Ab + (size_t)(row0 + lr[i]) * kD + k0 + lg[i] * 8,
              &Asm[(i * 256 + wave * 64) * 8]);
    }
#pragma unroll
    for (int i = 0; i < 2; ++i)
      GLD16(BT + (size_t)(col0 + lr[i]) * kD + k0 + lg[i] * 8,
            &Bsm[(i * 256 + wave * 64) * 8]);
    __syncthreads();

    bf16x8 af[4], br[4];
#pragma unroll
    for (int mi = 0; mi < 4; ++mi)
      af[mi] = *(const bf16x8*)&Asm[(wm + mi * 16 + l15) * 32 + (qd ^ sw) * 8];
#pragma unroll
    for (int ni = 0; ni < 4; ++ni)
      br[ni] = *(const bf16x8*)&Bsm[(wn + ni * 16 + l15) * 32 + (qd ^ sw) * 8];
#pragma unroll
    for (int mi = 0; mi < 4; ++mi)
#pragma unroll
      for (int ni = 0; ni < 4; ++ni)
        acc[mi][ni] = __builtin_amdgcn_mfma_f32_16x16x32_bf16(
            af[mi], br[ni], acc[mi][ni], 0, 0, 0);
    __syncthreads();
  }

  float bcol[4];
#pragma unroll
  for (int ni = 0; ni < 4; ++ni) bcol[ni] = bias[col0 + wn + ni * 16 + l15];

  if (mode <= 1) {
    ushort* C = (mode == 0) ? Qp : Kp;
#pragma unroll
    for (int mi = 0; mi < 4; ++mi)
#pragma unroll
      for (int ni = 0; ni < 4; ++ni) {
        const int n_g = col0 + wn + ni * 16 + l15;
#pragma unroll
        for (int r = 0; r < 4; ++r) {
          const int token = row0 + wm + mi * 16 + qd * 4 + r;
          C[(size_t)token * kD + n_g] = f2bf(acc[mi][ni][r] + bcol[ni]);
        }
      }
  } else if (mode == 2) {
#pragma unroll
    for (int mi = 0; mi < 4; ++mi)
#pragma unroll
      for (int ni = 0; ni < 4; ++ni) {
        const int n_g = col0 + wn + ni * 16 + l15;
        const int h = n_g >> 6, d = n_g & 63;
        const int t0 = row0 + wm + mi * 16 + qd * 4;
        const int b = t0 >> 11, ss = t0 & (kS - 1);
        alignas(8) ushort t4[4];
#pragma unroll
        for (int r = 0; r < 4; ++r) t4[r] = f2bf(acc[mi][ni][r] + bcol[ni]);
        *(uint2*)&VT[((size_t)(b * kH + h) * 64 + d) * kS + ss] =
            *(const uint2*)t4;
      }
  } else {
#pragma unroll
    for (int mi = 0; mi < 4; ++mi)
#pragma unroll
      for (int ni = 0; ni < 4; ++ni) {
        const int n_g = col0 + wn + ni * 16 + l15;
#pragma unroll
        for (int r = 0; r < 4; ++r) {
          const int token = row0 + wm + mi * 16 + qd * 4 + r;
          outp[(size_t)token * kD + n_g] = acc[mi][ni][r] + bcol[ni];
        }
      }
  }
}

// ---------------------------------------------------------------------------
// MFMA banded attention. One wave per 64-query tile per (b,h). grid (32,32).
// S = Q @ K^T over 96 keys (band +/-16), mask, softmax, P (via LDS) @ V.
// ---------------------------------------------------------------------------
__global__ __launch_bounds__(64, 1) void attn_kernel(
    const ushort* __restrict__ Qp, const ushort* __restrict__ Kp,
    const ushort* __restrict__ VT, ushort* __restrict__ Ob) {
  __shared__ alignas(16) ushort Pl[64 * 104];  // [query][96 keys], stride 104

  const int lane = threadIdx.x, l15 = lane & 15, qd = lane >> 4;
  const int bh = blockIdx.y, b = bh >> 3, h = bh & 7;
  const int q0 = blockIdx.x * 64;
  const int colA = h * 64;

  // Q fragments (A-layout): lane = query row, 8 contiguous d per quad
  bf16x8 qf[4][2], kf[6][2];
#pragma unroll
  for (int mi = 0; mi < 4; ++mi) {
    const size_t base =
        ((size_t)b * kS + q0 + mi * 16 + l15) * kD + colA + qd * 8;
#pragma unroll
    for (int kc = 0; kc < 2; ++kc)
      qf[mi][kc] = *(const bf16x8*)&Qp[base + kc * 32];
  }
  // K fragments (B-layout): lane = key row, 8 contiguous d per quad
#pragma unroll
  for (int ni = 0; ni < 6; ++ni) {
    int key = q0 - kBand + ni * 16 + l15;
    key = key < 0 ? 0 : (key > kS - 1 ? kS - 1 : key);  // clamp; masked below
    const size_t base = ((size_t)b * kS + key) * kD + colA + qd * 8;
#pragma unroll
    for (int kc = 0; kc < 2; ++kc)
      kf[ni][kc] = *(const bf16x8*)&Kp[base + kc * 32];
  }

  f32x4 S[4][6];
#pragma unroll
  for (int mi = 0; mi < 4; ++mi)
#pragma unroll
    for (int ni = 0; ni < 6; ++ni) S[mi][ni] = (f32x4)(0.f);
#pragma unroll
  for (int mi = 0; mi < 4; ++mi)
#pragma unroll
    for (int ni = 0; ni < 6; ++ni)
#pragma unroll
      for (int kc = 0; kc < 2; ++kc)
        S[mi][ni] = __builtin_amdgcn_mfma_f32_16x16x32_bf16(
            qf[mi][kc], kf[ni][kc], S[mi][ni], 0, 0, 0);

  // mask + scale (C-layout: row = qd*4+r, col = l15)
#pragma unroll
  for (int mi = 0; mi < 4; ++mi)
#pragma unroll
    for (int ni = 0; ni < 6; ++ni)
#pragma unroll
      for (int r = 0; r < 4; ++r) {
        const int q_local = mi * 16 + qd * 4 + r;
        const int key_local = ni * 16 + l15;
        const int key = q0 - kBand + key_local;
        const int dlt = key_local - q_local;  // key-q+16 in [0,32] iff in band
        const bool ok = (dlt >= 0) && (dlt <= 32) && (key >= 0) && (key < kS);
        S[mi][ni][r] = ok ? S[mi][ni][r] * 0.125f : -3.0e38f;
      }

  // softmax per row: reduce over ni in-reg, then across 16 lanes
  float inv[4][4];
#pragma unroll
  for (int mi = 0; mi < 4; ++mi)
#pragma unroll
    for (int r = 0; r < 4; ++r) {
      float m = S[mi][0][r];
#pragma unroll
      for (int ni = 1; ni < 6; ++ni) m = fmaxf(m, S[mi][ni][r]);
      m = fmaxf(m, __shfl_xor(m, 1));
      m = fmaxf(m, __shfl_xor(m, 2));
      m = fmaxf(m, __shfl_xor(m, 4));
      m = fmaxf(m, __shfl_xor(m, 8));
      float s = 0.f;
#pragma unroll
      for (int ni = 0; ni < 6; ++ni) {
        const float e = __expf(S[mi][ni][r] - m);
        S[mi][ni][r] = e;
        s += e;
      }
      s += __shfl_xor(s, 1);
      s += __shfl_xor(s, 2);
      s += __shfl_xor(s, 4);
      s += __shfl_xor(s, 8);
      inv[mi][r] = 1.f / s;
    }

  // P -> LDS (C-layout scatter), then read back in A-layout
#pragma unroll
  for (int mi = 0; mi < 4; ++mi)
#pragma unroll
    for (int ni = 0; ni < 6; ++ni)
#pragma unroll
      for (int r = 0; r < 4; ++r)
        Pl[(mi * 16 + qd * 4 + r) * 104 + ni * 16 + l15] = f2bf(S[mi][ni][r]);
  __syncthreads();

  f32x4 O[4][4];
#pragma unroll
  for (int mi = 0; mi < 4; ++mi)
#pragma unroll
    for (int nt = 0; nt < 4; ++nt) O[mi][nt] = (f32x4)(0.f);

#pragma unroll
  for (int kc = 0; kc < 3; ++kc) {
    bf16x8 pf[4], vfr[4];
#pragma unroll
    for (int mi = 0; mi < 4; ++mi)
      pf[mi] = *(const bf16x8*)&Pl[(mi * 16 + l15) * 104 + kc * 32 + qd * 8];
    int kb0 = q0 - kBand + kc * 32 + qd * 8;
    kb0 = kb0 < 0 ? 0 : (kb0 > kS - 8 ? kS - 8 : kb0);  // clamp; P=0 there
#pragma unroll
    for (int nt = 0; nt < 4; ++nt)
      vfr[nt] = *(const bf16x8*)&VT[((size_t)bh * 64 + nt * 16 + l15) * kS + kb0];
#pragma unroll
    for (int mi = 0; mi < 4; ++mi)
#pragma unroll
      for (int nt = 0; nt < 4; ++nt)
        O[mi][nt] = __builtin_amdgcn_mfma_f32_16x16x32_bf16(pf[mi], vfr[nt],
                                                            O[mi][nt], 0, 0, 0);
  }

#pragma unroll
  for (int mi = 0; mi < 4; ++mi)
#pragma unroll
    for (int nt = 0; nt < 4; ++nt)
#pragma unroll
      for (int r = 0; r < 4; ++r) {
        const int tok = b * kS + q0 + mi * 16 + qd * 4 + r;
        Ob[(size_t)tok * kD + colA + nt * 16 + l15] =
            f2bf(O[mi][nt][r] * inv[mi][r]);
      }
}

extern "C" void kernel_launch(void* const* d_in, const int* in_sizes, int n_in,
                              void* d_out, int out_size, void* d_ws,
                              size_t ws_size, hipStream_t stream) {
  const float* q = (const float*)d_in[0];
  const float* k = (const float*)d_in[1];
  const float* v = (const float*)d_in[2];
  const float* wq = (const float*)d_in[3];
  const float* bq = (const float*)d_in[4];
  const float* wk = (const float*)d_in[5];
  const float* bk = (const float*)d_in[6];
  const float* wv = (const float*)d_in[7];
  const float* bv = (const float*)d_in[8];
  const float* wo = (const float*)d_in[9];
  const float* bo = (const float*)d_in[10];
  float* out = (float*)d_out;

  // ws (42 MB): qb | kb | Qp | Kp | VT | WT.  Ob aliases qb (dead after qkv).
  ushort* qb = (ushort*)d_ws;
  ushort* kb = qb + (size_t)kNT * kD;
  ushort* Qp = kb + (size_t)kNT * kD;
  ushort* Kp = Qp + (size_t)kNT * kD;
  ushort* VT = Kp + (size_t)kNT * kD;
  ushort* WT = VT + (size_t)kNT * kD;
  ushort* Ob = qb;

  prep_w_kernel<<<dim3(8, 8, 4), 256, 0, stream>>>(wq, wk, wv, wo, WT);
  prep_act_kernel<<<dim3(2048, 2), 256, 0, stream>>>(q, k, qb, kb);
  gemm_kernel<<<dim3(4, 64, 3), 256, 0, stream>>>(
      qb, kb, v, Ob, WT, bq, bk, bv, bo, Qp, Kp, VT, out, 0);
  attn_kernel<<<dim3(kS / 64, 32), 64, 0, stream>>>(Qp, Kp, VT, Ob);
  gemm_kernel<<<dim3(4, 64, 1), 256, 0, stream>>>(
      qb, kb, v, Ob, WT, bq, bk, bv, bo, Qp, Kp, VT, out, 3);
}

// Round 5
// 170.285 us; speedup vs baseline: 2.3277x; 1.0623x over previous
//
#include <hip/hip_runtime.h>

typedef unsigned int uint;
typedef unsigned short ushort;
typedef __attribute__((ext_vector_type(8))) short bf16x8;
typedef __attribute__((ext_vector_type(4))) float f32x4;

namespace {
constexpr int kS = 2048;
constexpr int kD = 512;
constexpr int kH = 8;
constexpr int kNT = 8192;  // B*S
constexpr int kBand = 16;
}  // namespace

static __device__ __forceinline__ ushort f2bf(float f) {
  uint u = __builtin_bit_cast(uint, f);
  u = (u + 0x7fffu + ((u >> 16) & 1u)) >> 16;  // RNE
  return (ushort)u;
}

// global -> LDS direct DMA, 16B/lane. LDS dest = wave-uniform base + lane*16.
#define GLD16(gp, lp)                                                   \
  __builtin_amdgcn_global_load_lds(                                     \
      (const __attribute__((address_space(1))) uint*)(gp),              \
      (__attribute__((address_space(3))) uint*)(lp), 16, 0, 0)

// ---------------------------------------------------------------------------
// Fused prep: blocks [0,6144): q/k/v fp32 -> bf16 row-major (qb/kb/vb).
//             blocks [6144,6400): WT[z][n][k] = bf16(W[z][k][n]).
// ---------------------------------------------------------------------------
__global__ __launch_bounds__(256) void prep_kernel(
    const float* __restrict__ q, const float* __restrict__ k,
    const float* __restrict__ v, const float* __restrict__ wq,
    const float* __restrict__ wk, const float* __restrict__ wv,
    const float* __restrict__ wo, ushort* __restrict__ qb,
    ushort* __restrict__ kb, ushort* __restrict__ vb,
    ushort* __restrict__ WT) {
  __shared__ float Ws[64][65];
  const int blk = blockIdx.x;
  const int tid = threadIdx.x;
  if (blk < 6144) {
    const int z = blk >> 11, t = blk & 2047;
    const float* src = z == 0 ? q : (z == 1 ? k : v);
    ushort* dst = z == 0 ? qb : (z == 1 ? kb : vb);
    const size_t i8 = ((size_t)t * 256 + tid) * 8;
    const float4 x0 = *(const float4*)(src + i8);
    const float4 x1 = *(const float4*)(src + i8 + 4);
    alignas(16) ushort t8[8] = {f2bf(x0.x), f2bf(x0.y), f2bf(x0.z), f2bf(x0.w),
                                f2bf(x1.x), f2bf(x1.y), f2bf(x1.z), f2bf(x1.w)};
    *(uint4*)(dst + i8) = *(const uint4*)t8;
    return;
  }
  const int w = blk - 6144;  // 0..255
  const int z = w >> 6;
  const float* W = z == 0 ? wq : (z == 1 ? wk : (z == 2 ? wv : wo));
  ushort* T = WT + (size_t)z * kD * kD;
  const int kt = ((w >> 3) & 7) * 64, nt = (w & 7) * 64;
  const int r = tid >> 2, c0 = (tid & 3) * 16;
#pragma unroll
  for (int i = 0; i < 4; ++i) {
    const float4 x =
        *(const float4*)(W + (size_t)(kt + r) * kD + nt + c0 + i * 4);
    Ws[r][c0 + i * 4 + 0] = x.x;
    Ws[r][c0 + i * 4 + 1] = x.y;
    Ws[r][c0 + i * 4 + 2] = x.z;
    Ws[r][c0 + i * 4 + 3] = x.w;
  }
  __syncthreads();
  const int n = tid >> 2, k0 = (tid & 3) * 16;
  alignas(16) ushort tmp[16];
#pragma unroll
  for (int i = 0; i < 16; ++i) tmp[i] = f2bf(Ws[k0 + i][n]);
  ushort* dst = T + (size_t)(nt + n) * kD + kt + k0;
  *(uint4*)(dst + 0) = *(const uint4*)&tmp[0];
  *(uint4*)(dst + 8) = *(const uint4*)&tmp[8];
}

// ---------------------------------------------------------------------------
// 128x128 BK=32 bf16 MFMA GEMM, 3-stage global_load_lds pipeline, one raw
// s_barrier + vmcnt(4) per iter (no full drain until the last stage).
// mode = mode_arg + blockIdx.z:
//   0: qb @ WTq + bq -> Qp (bf16 [tok][512])
//   1: kb @ WTk + bk -> Kp (bf16 [tok][512])
//   2: vb @ WTv + bv -> VT (bf16 [bh*64+d][2048], transposed)
//   3: ob @ WTo + bo -> out (fp32 [tok][512])
// ---------------------------------------------------------------------------
__global__ __launch_bounds__(256) void gemm_kernel(
    const ushort* __restrict__ qb, const ushort* __restrict__ kb,
    const ushort* __restrict__ vb, const ushort* __restrict__ obp,
    const ushort* __restrict__ WT, const float* __restrict__ bq,
    const float* __restrict__ bk, const float* __restrict__ bv,
    const float* __restrict__ bo, ushort* __restrict__ Qp,
    ushort* __restrict__ Kp, ushort* __restrict__ VT,
    float* __restrict__ outp, int mode_arg) {
  const int mode = mode_arg + blockIdx.z;
  const ushort* Ab;
  const float* bias;
  switch (mode) {
    case 0: Ab = qb; bias = bq; break;
    case 1: Ab = kb; bias = bk; break;
    case 2: Ab = vb; bias = bv; break;
    default: Ab = obp; bias = bo; break;
  }
  const ushort* BT = WT + (size_t)mode * kD * kD;

  // 48 KB: A stages at [st*4096], B stages at [12288 + st*4096] (ushort idx).
  // Rows of 32 bf16 = 4 x 16B chunks; chunk c of row r holds global chunk
  // c ^ s(r), s(r) = (r&3)^((r>>2)&3). No padding (DMA requires contiguity).
  __shared__ alignas(16) ushort smem[24576];

  const int tid = threadIdx.x;
  const int wave = tid >> 6, lane = tid & 63, l15 = lane & 15, qd = lane >> 4;
  const int wm = (wave >> 1) * 64, wn = (wave & 1) * 64;
  const int row0 = blockIdx.y * 128, col0 = blockIdx.x * 128;
  const int sw = (l15 & 3) ^ (l15 >> 2);  // = s(row) for all frag rows

  // loader mapping: 2 DMA issues x 256 lanes x 16B per tile per stage
  const ushort* pA[2];
  const ushort* pB[2];
  uint ldsA[2], ldsB[2];
#pragma unroll
  for (int i = 0; i < 2; ++i) {
    const int linear = i * 256 + tid;
    const int r = linear >> 2, c = linear & 3;
    const int g = c ^ ((r & 3) ^ ((r >> 2) & 3));
    pA[i] = Ab + (size_t)(row0 + r) * kD + g * 8;
    pB[i] = BT + (size_t)(col0 + r) * kD + g * 8;
    ldsA[i] = (uint)(i * 256 + wave * 64) * 8;
    ldsB[i] = 12288u + (uint)(i * 256 + wave * 64) * 8;
  }

#define ISSUE(kk, st)                                  \
  {                                                    \
    GLD16(pA[0] + (kk), &smem[ldsA[0] + (st) * 4096]); \
    GLD16(pA[1] + (kk), &smem[ldsA[1] + (st) * 4096]); \
    GLD16(pB[0] + (kk), &smem[ldsB[0] + (st) * 4096]); \
    GLD16(pB[1] + (kk), &smem[ldsB[1] + (st) * 4096]); \
  }

  f32x4 acc[4][4];
#pragma unroll
  for (int mi = 0; mi < 4; ++mi)
#pragma unroll
    for (int ni = 0; ni < 4; ++ni) acc[mi][ni] = (f32x4)(0.f);

  ISSUE(0, 0);
  ISSUE(32, 1);
#pragma unroll
  for (int it = 0; it < 16; ++it) {
    if (it < 15)
      asm volatile("s_waitcnt vmcnt(4) lgkmcnt(0)\n\ts_barrier" ::: "memory");
    else
      asm volatile("s_waitcnt vmcnt(0) lgkmcnt(0)\n\ts_barrier" ::: "memory");
    if (it < 14) ISSUE((it + 2) * 32, (it + 2) % 3);
    const ushort* as = &smem[(it % 3) * 4096];
    const ushort* bs = &smem[12288 + (it % 3) * 4096];
    bf16x8 af[4], br[4];
#pragma unroll
    for (int mi = 0; mi < 4; ++mi)
      af[mi] = *(const bf16x8*)&as[(wm + mi * 16 + l15) * 32 + (qd ^ sw) * 8];
#pragma unroll
    for (int ni = 0; ni < 4; ++ni)
      br[ni] = *(const bf16x8*)&bs[(wn + ni * 16 + l15) * 32 + (qd ^ sw) * 8];
#pragma unroll
    for (int mi = 0; mi < 4; ++mi)
#pragma unroll
      for (int ni = 0; ni < 4; ++ni)
        acc[mi][ni] = __builtin_amdgcn_mfma_f32_16x16x32_bf16(
            af[mi], br[ni], acc[mi][ni], 0, 0, 0);
  }
#undef ISSUE

  __syncthreads();  // safe to reuse smem for the epilogue transpose

  float bcol[4];
#pragma unroll
  for (int ni = 0; ni < 4; ++ni) bcol[ni] = bias[col0 + wn + ni * 16 + l15];

  if (mode == 3) {  // fp32 direct stores
#pragma unroll
    for (int mi = 0; mi < 4; ++mi)
#pragma unroll
      for (int ni = 0; ni < 4; ++ni) {
        const int n_g = col0 + wn + ni * 16 + l15;
#pragma unroll
        for (int r = 0; r < 4; ++r) {
          const int token = row0 + wm + mi * 16 + qd * 4 + r;
          outp[(size_t)token * kD + n_g] = acc[mi][ni][r] + bcol[ni];
        }
      }
    return;
  }

  // bf16 outputs: per-wave 64x64 transpose through LDS (stride 72 ushorts =
  // 144 B, 16B-aligned rows), then 8 x dwordx4 global stores per lane.
  ushort* T = &smem[wave * 4608];
  if (mode <= 1) {  // place [token_local][d_local]
#pragma unroll
    for (int mi = 0; mi < 4; ++mi)
#pragma unroll
      for (int ni = 0; ni < 4; ++ni)
#pragma unroll
        for (int r = 0; r < 4; ++r)
          T[(mi * 16 + qd * 4 + r) * 72 + ni * 16 + l15] =
              f2bf(acc[mi][ni][r] + bcol[ni]);
  } else {  // mode 2: place [d_local][token_local]
#pragma unroll
    for (int mi = 0; mi < 4; ++mi)
#pragma unroll
      for (int ni = 0; ni < 4; ++ni)
#pragma unroll
        for (int r = 0; r < 4; ++r)
          T[(ni * 16 + l15) * 72 + mi * 16 + qd * 4 + r] =
              f2bf(acc[mi][ni][r] + bcol[ni]);
  }
  asm volatile("s_waitcnt lgkmcnt(0)" ::: "memory");  // wave-local visibility

  const ushort* Trow = &smem[wave * 4608 + lane * 72];
  if (mode <= 1) {
    ushort* C = (mode == 0) ? Qp : Kp;
    ushort* dst = C + (size_t)(row0 + wm + lane) * kD + col0 + wn;
#pragma unroll
    for (int c = 0; c < 8; ++c)
      *(uint4*)(dst + c * 8) = *(const uint4*)(Trow + c * 8);
  } else {
    const int n_g = col0 + wn + lane;
    const int h = n_g >> 6, d = n_g & 63;
    const int t0 = row0 + wm;
    const int b = t0 >> 11, ss = t0 & (kS - 1);
    ushort* dst = VT + ((size_t)(b * kH + h) * 64 + d) * kS + ss;
#pragma unroll
    for (int c = 0; c < 8; ++c)
      *(uint4*)(dst + c * 8) = *(const uint4*)(Trow + c * 8);
  }
}

// ---------------------------------------------------------------------------
// MFMA banded attention. One wave per 64-query tile per (b,h). grid (32,32).
// ---------------------------------------------------------------------------
__global__ __launch_bounds__(64, 1) void attn_kernel(
    const ushort* __restrict__ Qp, const ushort* __restrict__ Kp,
    const ushort* __restrict__ VT, ushort* __restrict__ Ob) {
  __shared__ alignas(16) ushort Pl[64 * 104];  // P scatter; reused for O xpose

  const int lane = threadIdx.x, l15 = lane & 15, qd = lane >> 4;
  const int bh = blockIdx.y, b = bh >> 3, h = bh & 7;
  const int q0 = blockIdx.x * 64;
  const int colA = h * 64;

  bf16x8 qf[4][2], kf[6][2];
#pragma unroll
  for (int mi = 0; mi < 4; ++mi) {
    const size_t base =
        ((size_t)b * kS + q0 + mi * 16 + l15) * kD + colA + qd * 8;
#pragma unroll
    for (int kc = 0; kc < 2; ++kc)
      qf[mi][kc] = *(const bf16x8*)&Qp[base + kc * 32];
  }
#pragma unroll
  for (int ni = 0; ni < 6; ++ni) {
    int key = q0 - kBand + ni * 16 + l15;
    key = key < 0 ? 0 : (key > kS - 1 ? kS - 1 : key);  // clamp; masked below
    const size_t base = ((size_t)b * kS + key) * kD + colA + qd * 8;
#pragma unroll
    for (int kc = 0; kc < 2; ++kc)
      kf[ni][kc] = *(const bf16x8*)&Kp[base + kc * 32];
  }

  f32x4 S[4][6];
#pragma unroll
  for (int mi = 0; mi < 4; ++mi)
#pragma unroll
    for (int ni = 0; ni < 6; ++ni) S[mi][ni] = (f32x4)(0.f);
#pragma unroll
  for (int mi = 0; mi < 4; ++mi)
#pragma unroll
    for (int ni = 0; ni < 6; ++ni)
#pragma unroll
      for (int kc = 0; kc < 2; ++kc)
        S[mi][ni] = __builtin_amdgcn_mfma_f32_16x16x32_bf16(
            qf[mi][kc], kf[ni][kc], S[mi][ni], 0, 0, 0);

#pragma unroll
  for (int mi = 0; mi < 4; ++mi)
#pragma unroll
    for (int ni = 0; ni < 6; ++ni)
#pragma unroll
      for (int r = 0; r < 4; ++r) {
        const int q_local = mi * 16 + qd * 4 + r;
        const int key_local = ni * 16 + l15;
        const int key = q0 - kBand + key_local;
        const int dlt = key_local - q_local;
        const bool ok = (dlt >= 0) && (dlt <= 32) && (key >= 0) && (key < kS);
        S[mi][ni][r] = ok ? S[mi][ni][r] * 0.125f : -3.0e38f;
      }

  float inv[4][4];
#pragma unroll
  for (int mi = 0; mi < 4; ++mi)
#pragma unroll
    for (int r = 0; r < 4; ++r) {
      float m = S[mi][0][r];
#pragma unroll
      for (int ni = 1; ni < 6; ++ni) m = fmaxf(m, S[mi][ni][r]);
      m = fmaxf(m, __shfl_xor(m, 1));
      m = fmaxf(m, __shfl_xor(m, 2));
      m = fmaxf(m, __shfl_xor(m, 4));
      m = fmaxf(m, __shfl_xor(m, 8));
      float s = 0.f;
#pragma unroll
      for (int ni = 0; ni < 6; ++ni) {
        const float e = __expf(S[mi][ni][r] - m);
        S[mi][ni][r] = e;
        s += e;
      }
      s += __shfl_xor(s, 1);
      s += __shfl_xor(s, 2);
      s += __shfl_xor(s, 4);
      s += __shfl_xor(s, 8);
      inv[mi][r] = 1.f / s;
    }

  // P -> LDS (C-layout scatter, stride 104), read back in A-layout
#pragma unroll
  for (int mi = 0; mi < 4; ++mi)
#pragma unroll
    for (int ni = 0; ni < 6; ++ni)
#pragma unroll
      for (int r = 0; r < 4; ++r)
        Pl[(mi * 16 + qd * 4 + r) * 104 + ni * 16 + l15] = f2bf(S[mi][ni][r]);
  __syncthreads();

  f32x4 O[4][4];
#pragma unroll
  for (int mi = 0; mi < 4; ++mi)
#pragma unroll
    for (int nt = 0; nt < 4; ++nt) O[mi][nt] = (f32x4)(0.f);

#pragma unroll
  for (int kc = 0; kc < 3; ++kc) {
    bf16x8 pf[4], vfr[4];
#pragma unroll
    for (int mi = 0; mi < 4; ++mi)
      pf[mi] = *(const bf16x8*)&Pl[(mi * 16 + l15) * 104 + kc * 32 + qd * 8];
    int kb0 = q0 - kBand + kc * 32 + qd * 8;
    kb0 = kb0 < 0 ? 0 : (kb0 > kS - 8 ? kS - 8 : kb0);  // clamp; P=0 there
#pragma unroll
    for (int nt = 0; nt < 4; ++nt)
      vfr[nt] =
          *(const bf16x8*)&VT[((size_t)bh * 64 + nt * 16 + l15) * kS + kb0];
#pragma unroll
    for (int mi = 0; mi < 4; ++mi)
#pragma unroll
      for (int nt = 0; nt < 4; ++nt)
        O[mi][nt] = __builtin_amdgcn_mfma_f32_16x16x32_bf16(pf[mi], vfr[nt],
                                                            O[mi][nt], 0, 0, 0);
  }

  // O transpose through LDS (reuse Pl, stride 72), 8 x dwordx4 stores/lane
#pragma unroll
  for (int mi = 0; mi < 4; ++mi)
#pragma unroll
    for (int nt = 0; nt < 4; ++nt)
#pragma unroll
      for (int r = 0; r < 4; ++r)
        Pl[(mi * 16 + qd * 4 + r) * 72 + nt * 16 + l15] =
            f2bf(O[mi][nt][r] * inv[mi][r]);
  asm volatile("s_waitcnt lgkmcnt(0)" ::: "memory");

  ushort* dst = Ob + ((size_t)b * kS + q0 + lane) * kD + colA;
  const ushort* Trow = &Pl[lane * 72];
#pragma unroll
  for (int c = 0; c < 8; ++c)
    *(uint4*)(dst + c * 8) = *(const uint4*)(Trow + c * 8);
}

extern "C" void kernel_launch(void* const* d_in, const int* in_sizes, int n_in,
                              void* d_out, int out_size, void* d_ws,
                              size_t ws_size, hipStream_t stream) {
  const float* q = (const float*)d_in[0];
  const float* k = (const float*)d_in[1];
  const float* v = (const float*)d_in[2];
  const float* wq = (const float*)d_in[3];
  const float* bq = (const float*)d_in[4];
  const float* wk = (const float*)d_in[5];
  const float* bk = (const float*)d_in[6];
  const float* wv = (const float*)d_in[7];
  const float* bv = (const float*)d_in[8];
  const float* wo = (const float*)d_in[9];
  const float* bo = (const float*)d_in[10];
  float* out = (float*)d_out;

  // ws (42 MB): qb | kb | vb | Kp | VT | WT.
  // Aliases (launch-order serialized): Qp <- vb (vb dead after gemm launch 1),
  // Ob <- kb (kb dead after gemm launch 1).
  ushort* qb = (ushort*)d_ws;
  ushort* kb = qb + (size_t)kNT * kD;
  ushort* vb = kb + (size_t)kNT * kD;
  ushort* Kp = vb + (size_t)kNT * kD;
  ushort* VT = Kp + (size_t)kNT * kD;
  ushort* WT = VT + (size_t)kNT * kD;
  ushort* Qp = vb;
  ushort* Ob = kb;

  prep_kernel<<<dim3(6400), 256, 0, stream>>>(q, k, v, wq, wk, wv, wo, qb, kb,
                                              vb, WT);
  gemm_kernel<<<dim3(4, 64, 2), 256, 0, stream>>>(  // modes 1,2: Kp, VT
      qb, kb, vb, Ob, WT, bq, bk, bv, bo, Qp, Kp, VT, out, 1);
  gemm_kernel<<<dim3(4, 64, 1), 256, 0, stream>>>(  // mode 0: Qp (<- vb)
      qb, kb, vb, Ob, WT, bq, bk, bv, bo, Qp, Kp, VT, out, 0);
  attn_kernel<<<dim3(kS / 64, 32), 64, 0, stream>>>(Qp, Kp, VT, Ob);
  gemm_kernel<<<dim3(4, 64, 1), 256, 0, stream>>>(  // mode 3: out
      qb, kb, vb, Ob, WT, bq, bk, bv, bo, Qp, Kp, VT, out, 3);
}

// Round 7
// 161.844 us; speedup vs baseline: 2.4491x; 1.0522x over previous
//
#include <hip/hip_runtime.h>

typedef unsigned int uint;
typedef unsigned short ushort;
typedef __attribute__((ext_vector_type(8))) short bf16x8;
typedef __attribute__((ext_vector_type(4))) float f32x4;

namespace {
constexpr int kS = 2048;
constexpr int kD = 512;
constexpr int kH = 8;
constexpr int kNT = 8192;  // B*S
constexpr int kBand = 16;
}  // namespace

static __device__ __forceinline__ ushort f2bf(float f) {
  uint u = __builtin_bit_cast(uint, f);
  u = (u + 0x7fffu + ((u >> 16) & 1u)) >> 16;  // RNE
  return (ushort)u;
}

// global -> LDS direct DMA, 16B/lane. LDS dest = wave-uniform base + lane*16.
#define GLD16(gp, lp)                                                   \
  __builtin_amdgcn_global_load_lds(                                     \
      (const __attribute__((address_space(1))) uint*)(gp),              \
      (__attribute__((address_space(3))) uint*)(lp), 16, 0, 0)

// ---------------------------------------------------------------------------
// Fused prep: blocks [0,6144): q/k/v fp32 -> bf16 row-major (qb/kb/vb).
//             blocks [6144,6400): WT[z][n][k] = bf16(W[z][k][n]).
// ---------------------------------------------------------------------------
__global__ __launch_bounds__(256) void prep_kernel(
    const float* __restrict__ q, const float* __restrict__ k,
    const float* __restrict__ v, const float* __restrict__ wq,
    const float* __restrict__ wk, const float* __restrict__ wv,
    const float* __restrict__ wo, ushort* __restrict__ qb,
    ushort* __restrict__ kb, ushort* __restrict__ vb,
    ushort* __restrict__ WT) {
  __shared__ float Ws[64][65];
  const int blk = blockIdx.x;
  const int tid = threadIdx.x;
  if (blk < 6144) {
    const int z = blk >> 11, t = blk & 2047;
    const float* src = z == 0 ? q : (z == 1 ? k : v);
    ushort* dst = z == 0 ? qb : (z == 1 ? kb : vb);
    const size_t i8 = ((size_t)t * 256 + tid) * 8;
    const float4 x0 = *(const float4*)(src + i8);
    const float4 x1 = *(const float4*)(src + i8 + 4);
    alignas(16) ushort t8[8] = {f2bf(x0.x), f2bf(x0.y), f2bf(x0.z), f2bf(x0.w),
                                f2bf(x1.x), f2bf(x1.y), f2bf(x1.z), f2bf(x1.w)};
    *(uint4*)(dst + i8) = *(const uint4*)t8;
    return;
  }
  const int w = blk - 6144;  // 0..255
  const int z = w >> 6;
  const float* W = z == 0 ? wq : (z == 1 ? wk : (z == 2 ? wv : wo));
  ushort* T = WT + (size_t)z * kD * kD;
  const int kt = ((w >> 3) & 7) * 64, nt = (w & 7) * 64;
  const int r = tid >> 2, c0 = (tid & 3) * 16;
#pragma unroll
  for (int i = 0; i < 4; ++i) {
    const float4 x =
        *(const float4*)(W + (size_t)(kt + r) * kD + nt + c0 + i * 4);
    Ws[r][c0 + i * 4 + 0] = x.x;
    Ws[r][c0 + i * 4 + 1] = x.y;
    Ws[r][c0 + i * 4 + 2] = x.z;
    Ws[r][c0 + i * 4 + 3] = x.w;
  }
  __syncthreads();
  const int n = tid >> 2, k0 = (tid & 3) * 16;
  alignas(16) ushort tmp[16];
#pragma unroll
  for (int i = 0; i < 16; ++i) tmp[i] = f2bf(Ws[k0 + i][n]);
  ushort* dst = T + (size_t)(nt + n) * kD + kt + k0;
  *(uint4*)(dst + 0) = *(const uint4*)&tmp[0];
  *(uint4*)(dst + 8) = *(const uint4*)&tmp[8];
}

// ---------------------------------------------------------------------------
// TM x 128 BK=32 bf16 MFMA GEMM, 3-stage global_load_lds pipeline, one raw
// s_barrier + vmcnt(loads-per-stage) per iter. TM=128: 4 waves, 2x2 of 64x64.
// TM=64: 4 waves side-by-side, each 64 rows x 32 cols.
// mode = mode_arg + blockIdx.z:
//   0: qb @ WTq + bq -> Qp (bf16 [tok][512])
//   1: kb @ WTk + bk -> Kp (bf16 [tok][512])
//   2: vb @ WTv + bv -> VT (bf16 [bh*64+d][2048], transposed)
//   3: ob @ WTo + bo -> out (fp32 [tok][512])
// ---------------------------------------------------------------------------
template <int TM>
__global__ __launch_bounds__(256) void gemm_kernel(
    const ushort* __restrict__ qb, const ushort* __restrict__ kb,
    const ushort* __restrict__ vb, const ushort* __restrict__ obp,
    const ushort* __restrict__ WT, const float* __restrict__ bq,
    const float* __restrict__ bk, const float* __restrict__ bv,
    const float* __restrict__ bo, ushort* __restrict__ Qp,
    ushort* __restrict__ Kp, ushort* __restrict__ VT,
    float* __restrict__ outp, int mode_arg) {
  const int mode = mode_arg + blockIdx.z;
  const ushort* Ab;
  const float* bias;
  switch (mode) {
    case 0: Ab = qb; bias = bq; break;
    case 1: Ab = kb; bias = bk; break;
    case 2: Ab = vb; bias = bv; break;
    default: Ab = obp; bias = bo; break;
  }
  const ushort* BT = WT + (size_t)mode * kD * kD;

  // A stages: [st * TM*32]; B stages: [3*TM*32 + st*4096] (ushort idx).
  // Rows of 32 bf16 = 4 x 16B chunks; chunk c of row r holds global chunk
  // c ^ s(r), s(r) = (r&3)^((r>>2)&3). No padding (DMA needs contiguity).
  constexpr int A_STAGE = TM * 32;
  constexpr int B_BASE = 3 * A_STAGE;
  constexpr int NI = (TM == 128) ? 4 : 2;
  constexpr int AI = TM / 64;  // A DMA issues per stage (x256 lanes x 16B)
  __shared__ alignas(16) ushort smem[B_BASE + 12288];

  const int tid = threadIdx.x;
  const int wave = tid >> 6, lane = tid & 63, l15 = lane & 15, qd = lane >> 4;
  const int wm = (TM == 128) ? (wave >> 1) * 64 : 0;
  const int wn = (TM == 128) ? (wave & 1) * 64 : wave * 32;
  const int row0 = blockIdx.y * TM, col0 = blockIdx.x * 128;
  const int sw = (l15 & 3) ^ (l15 >> 2);  // = s(row) for all frag rows

  const ushort* pA[AI];
  const ushort* pB[2];
  uint ldsA[AI], ldsB[2];
#pragma unroll
  for (int i = 0; i < AI; ++i) {
    const int linear = i * 256 + tid;
    const int r = linear >> 2, c = linear & 3;
    const int g = c ^ ((r & 3) ^ ((r >> 2) & 3));
    pA[i] = Ab + (size_t)(row0 + r) * kD + g * 8;
    ldsA[i] = (uint)(i * 256 + wave * 64) * 8;
  }
#pragma unroll
  for (int i = 0; i < 2; ++i) {
    const int linear = i * 256 + tid;
    const int r = linear >> 2, c = linear & 3;
    const int g = c ^ ((r & 3) ^ ((r >> 2) & 3));
    pB[i] = BT + (size_t)(col0 + r) * kD + g * 8;
    ldsB[i] = (uint)B_BASE + (uint)(i * 256 + wave * 64) * 8;
  }

#define ISSUE(kk, st)                                                     \
  {                                                                       \
    _Pragma("unroll") for (int i = 0; i < AI; ++i)                        \
        GLD16(pA[i] + (kk), &smem[ldsA[i] + (st) * A_STAGE]);             \
    _Pragma("unroll") for (int i = 0; i < 2; ++i)                         \
        GLD16(pB[i] + (kk), &smem[ldsB[i] + (st) * 4096]);                \
  }

  f32x4 acc[4][NI];
#pragma unroll
  for (int mi = 0; mi < 4; ++mi)
#pragma unroll
    for (int ni = 0; ni < NI; ++ni) acc[mi][ni] = (f32x4)(0.f);

  ISSUE(0, 0);
  ISSUE(32, 1);
#pragma unroll
  for (int it = 0; it < 16; ++it) {
    // vmcnt(N) must equal the loads-in-flight for the NEXT stage only:
    // one stage = AI+2 loads. TM=128 -> 4, TM=64 -> 3.
    if (it < 15) {
      if constexpr (TM == 128)
        asm volatile("s_waitcnt vmcnt(4) lgkmcnt(0)\n\ts_barrier" ::: "memory");
      else
        asm volatile("s_waitcnt vmcnt(3) lgkmcnt(0)\n\ts_barrier" ::: "memory");
    } else {
      asm volatile("s_waitcnt vmcnt(0) lgkmcnt(0)\n\ts_barrier" ::: "memory");
    }
    if (it < 14) ISSUE((it + 2) * 32, (it + 2) % 3);
    const ushort* as = &smem[(it % 3) * A_STAGE];
    const ushort* bs = &smem[B_BASE + (it % 3) * 4096];
    bf16x8 af[4], br[NI];
#pragma unroll
    for (int mi = 0; mi < 4; ++mi)
      af[mi] = *(const bf16x8*)&as[(wm + mi * 16 + l15) * 32 + (qd ^ sw) * 8];
#pragma unroll
    for (int ni = 0; ni < NI; ++ni)
      br[ni] = *(const bf16x8*)&bs[(wn + ni * 16 + l15) * 32 + (qd ^ sw) * 8];
#pragma unroll
    for (int mi = 0; mi < 4; ++mi)
#pragma unroll
      for (int ni = 0; ni < NI; ++ni)
        acc[mi][ni] = __builtin_amdgcn_mfma_f32_16x16x32_bf16(
            af[mi], br[ni], acc[mi][ni], 0, 0, 0);
  }
#undef ISSUE

  float bcol[NI];
#pragma unroll
  for (int ni = 0; ni < NI; ++ni) bcol[ni] = bias[col0 + wn + ni * 16 + l15];

  if (mode == 3) {  // fp32 direct stores
#pragma unroll
    for (int mi = 0; mi < 4; ++mi)
#pragma unroll
      for (int ni = 0; ni < NI; ++ni) {
        const int n_g = col0 + wn + ni * 16 + l15;
#pragma unroll
        for (int r = 0; r < 4; ++r) {
          const int token = row0 + wm + mi * 16 + qd * 4 + r;
          outp[(size_t)token * kD + n_g] = acc[mi][ni][r] + bcol[ni];
        }
      }
    return;
  }

  __syncthreads();  // safe to reuse smem for the epilogue transpose

  // bf16 outputs: per-wave 64x64 transpose through LDS (stride 72 ushorts),
  // then 8 x dwordx4 global stores per lane.
  ushort* T = &smem[wave * 4608];
  if (mode <= 1) {  // place [token_local][d_local]
#pragma unroll
    for (int mi = 0; mi < 4; ++mi)
#pragma unroll
      for (int ni = 0; ni < NI; ++ni)
#pragma unroll
        for (int r = 0; r < 4; ++r)
          T[(mi * 16 + qd * 4 + r) * 72 + ni * 16 + l15] =
              f2bf(acc[mi][ni][r] + bcol[ni]);
  } else {  // mode 2: place [d_local][token_local]
#pragma unroll
    for (int mi = 0; mi < 4; ++mi)
#pragma unroll
      for (int ni = 0; ni < NI; ++ni)
#pragma unroll
        for (int r = 0; r < 4; ++r)
          T[(ni * 16 + l15) * 72 + mi * 16 + qd * 4 + r] =
              f2bf(acc[mi][ni][r] + bcol[ni]);
  }
  asm volatile("s_waitcnt lgkmcnt(0)" ::: "memory");  // wave-local visibility

  const ushort* Trow = &smem[wave * 4608 + lane * 72];
  if (mode <= 1) {
    ushort* C = (mode == 0) ? Qp : Kp;
    ushort* dst = C + (size_t)(row0 + wm + lane) * kD + col0 + wn;
#pragma unroll
    for (int c = 0; c < 8; ++c)
      *(uint4*)(dst + c * 8) = *(const uint4*)(Trow + c * 8);
  } else {
    const int n_g = col0 + wn + lane;
    const int h = n_g >> 6, d = n_g & 63;
    const int t0 = row0 + wm;
    const int b = t0 >> 11, ss = t0 & (kS - 1);
    ushort* dst = VT + ((size_t)(b * kH + h) * 64 + d) * kS + ss;
#pragma unroll
    for (int c = 0; c < 8; ++c)
      *(uint4*)(dst + c * 8) = *(const uint4*)(Trow + c * 8);
  }
}

// ---------------------------------------------------------------------------
// MFMA banded attention. One wave per 64-query tile per (b,h). grid (32,32).
// ---------------------------------------------------------------------------
__global__ __launch_bounds__(64, 1) void attn_kernel(
    const ushort* __restrict__ Qp, const ushort* __restrict__ Kp,
    const ushort* __restrict__ VT, ushort* __restrict__ Ob) {
  __shared__ alignas(16) ushort Pl[64 * 104];  // P scatter; reused for O xpose

  const int lane = threadIdx.x, l15 = lane & 15, qd = lane >> 4;
  const int bh = blockIdx.y, b = bh >> 3, h = bh & 7;
  const int q0 = blockIdx.x * 64;
  const int colA = h * 64;

  bf16x8 qf[4][2], kf[6][2];
#pragma unroll
  for (int mi = 0; mi < 4; ++mi) {
    const size_t base =
        ((size_t)b * kS + q0 + mi * 16 + l15) * kD + colA + qd * 8;
#pragma unroll
    for (int kc = 0; kc < 2; ++kc)
      qf[mi][kc] = *(const bf16x8*)&Qp[base + kc * 32];
  }
#pragma unroll
  for (int ni = 0; ni < 6; ++ni) {
    int key = q0 - kBand + ni * 16 + l15;
    key = key < 0 ? 0 : (key > kS - 1 ? kS - 1 : key);  // clamp; masked below
    const size_t base = ((size_t)b * kS + key) * kD + colA + qd * 8;
#pragma unroll
    for (int kc = 0; kc < 2; ++kc)
      kf[ni][kc] = *(const bf16x8*)&Kp[base + kc * 32];
  }

  f32x4 S[4][6];
#pragma unroll
  for (int mi = 0; mi < 4; ++mi)
#pragma unroll
    for (int ni = 0; ni < 6; ++ni) S[mi][ni] = (f32x4)(0.f);
#pragma unroll
  for (int mi = 0; mi < 4; ++mi)
#pragma unroll
    for (int ni = 0; ni < 6; ++ni)
#pragma unroll
      for (int kc = 0; kc < 2; ++kc)
        S[mi][ni] = __builtin_amdgcn_mfma_f32_16x16x32_bf16(
            qf[mi][kc], kf[ni][kc], S[mi][ni], 0, 0, 0);

#pragma unroll
  for (int mi = 0; mi < 4; ++mi)
#pragma unroll
    for (int ni = 0; ni < 6; ++ni)
#pragma unroll
      for (int r = 0; r < 4; ++r) {
        const int q_local = mi * 16 + qd * 4 + r;
        const int key_local = ni * 16 + l15;
        const int key = q0 - kBand + key_local;
        const int dlt = key_local - q_local;
        const bool ok = (dlt >= 0) && (dlt <= 32) && (key >= 0) && (key < kS);
        S[mi][ni][r] = ok ? S[mi][ni][r] * 0.125f : -3.0e38f;
      }

  float inv[4][4];
#pragma unroll
  for (int mi = 0; mi < 4; ++mi)
#pragma unroll
    for (int r = 0; r < 4; ++r) {
      float m = S[mi][0][r];
#pragma unroll
      for (int ni = 1; ni < 6; ++ni) m = fmaxf(m, S[mi][ni][r]);
      m = fmaxf(m, __shfl_xor(m, 1));
      m = fmaxf(m, __shfl_xor(m, 2));
      m = fmaxf(m, __shfl_xor(m, 4));
      m = fmaxf(m, __shfl_xor(m, 8));
      float s = 0.f;
#pragma unroll
      for (int ni = 0; ni < 6; ++ni) {
        const float e = __expf(S[mi][ni][r] - m);
        S[mi][ni][r] = e;
        s += e;
      }
      s += __shfl_xor(s, 1);
      s += __shfl_xor(s, 2);
      s += __shfl_xor(s, 4);
      s += __shfl_xor(s, 8);
      inv[mi][r] = 1.f / s;
    }

  // P -> LDS (C-layout scatter, stride 104), read back in A-layout
#pragma unroll
  for (int mi = 0; mi < 4; ++mi)
#pragma unroll
    for (int ni = 0; ni < 6; ++ni)
#pragma unroll
      for (int r = 0; r < 4; ++r)
        Pl[(mi * 16 + qd * 4 + r) * 104 + ni * 16 + l15] = f2bf(S[mi][ni][r]);
  __syncthreads();

  f32x4 O[4][4];
#pragma unroll
  for (int mi = 0; mi < 4; ++mi)
#pragma unroll
    for (int nt = 0; nt < 4; ++nt) O[mi][nt] = (f32x4)(0.f);

#pragma unroll
  for (int kc = 0; kc < 3; ++kc) {
    bf16x8 pf[4], vfr[4];
#pragma unroll
    for (int mi = 0; mi < 4; ++mi)
      pf[mi] = *(const bf16x8*)&Pl[(mi * 16 + l15) * 104 + kc * 32 + qd * 8];
    int kb0 = q0 - kBand + kc * 32 + qd * 8;
    kb0 = kb0 < 0 ? 0 : (kb0 > kS - 8 ? kS - 8 : kb0);  // clamp; P=0 there
#pragma unroll
    for (int nt = 0; nt < 4; ++nt)
      vfr[nt] =
          *(const bf16x8*)&VT[((size_t)bh * 64 + nt * 16 + l15) * kS + kb0];
#pragma unroll
    for (int mi = 0; mi < 4; ++mi)
#pragma unroll
      for (int nt = 0; nt < 4; ++nt)
        O[mi][nt] = __builtin_amdgcn_mfma_f32_16x16x32_bf16(pf[mi], vfr[nt],
                                                            O[mi][nt], 0, 0, 0);
  }

  // O transpose through LDS (reuse Pl, stride 72), 8 x dwordx4 stores/lane
#pragma unroll
  for (int mi = 0; mi < 4; ++mi)
#pragma unroll
    for (int nt = 0; nt < 4; ++nt)
#pragma unroll
      for (int r = 0; r < 4; ++r)
        Pl[(mi * 16 + qd * 4 + r) * 72 + nt * 16 + l15] =
            f2bf(O[mi][nt][r] * inv[mi][r]);
  asm volatile("s_waitcnt lgkmcnt(0)" ::: "memory");

  ushort* dst = Ob + ((size_t)b * kS + q0 + lane) * kD + colA;
  const ushort* Trow = &Pl[lane * 72];
#pragma unroll
  for (int c = 0; c < 8; ++c)
    *(uint4*)(dst + c * 8) = *(const uint4*)(Trow + c * 8);
}

extern "C" void kernel_launch(void* const* d_in, const int* in_sizes, int n_in,
                              void* d_out, int out_size, void* d_ws,
                              size_t ws_size, hipStream_t stream) {
  const float* q = (const float*)d_in[0];
  const float* k = (const float*)d_in[1];
  const float* v = (const float*)d_in[2];
  const float* wq = (const float*)d_in[3];
  const float* bq = (const float*)d_in[4];
  const float* wk = (const float*)d_in[5];
  const float* bk = (const float*)d_in[6];
  const float* wv = (const float*)d_in[7];
  const float* bv = (const float*)d_in[8];
  const float* wo = (const float*)d_in[9];
  const float* bo = (const float*)d_in[10];
  float* out = (float*)d_out;

  // ws (~58 MB of the ~256 MB available), no aliasing:
  const size_t n1 = (size_t)kNT * kD;  // 4M ushorts = 8 MB
  ushort* qb = (ushort*)d_ws;
  ushort* kb = qb + n1;
  ushort* vb = kb + n1;
  ushort* Qp = vb + n1;
  ushort* Kp = Qp + n1;
  ushort* VT = Kp + n1;
  ushort* Ob = VT + n1;
  ushort* WT = Ob + n1;

  prep_kernel<<<dim3(6400), 256, 0, stream>>>(q, k, v, wq, wk, wv, wo, qb, kb,
                                              vb, WT);
  gemm_kernel<128><<<dim3(4, 64, 3), 256, 0, stream>>>(  // modes 0,1,2
      qb, kb, vb, Ob, WT, bq, bk, bv, bo, Qp, Kp, VT, out, 0);
  attn_kernel<<<dim3(kS / 64, 32), 64, 0, stream>>>(Qp, Kp, VT, Ob);
  gemm_kernel<64><<<dim3(4, 128, 1), 256, 0, stream>>>(  // mode 3
      qb, kb, vb, Ob, WT, bq, bk, bv, bo, Qp, Kp, VT, out, 3);
}

// Round 8
// 157.747 us; speedup vs baseline: 2.5127x; 1.0260x over previous
//
#include <hip/hip_runtime.h>

typedef unsigned int uint;
typedef unsigned short ushort;
typedef __attribute__((ext_vector_type(8))) short bf16x8;
typedef __attribute__((ext_vector_type(4))) float f32x4;

namespace {
constexpr int kS = 2048;
constexpr int kD = 512;
constexpr int kH = 8;
constexpr int kNT = 8192;  // B*S
constexpr int kBand = 16;
}  // namespace

static __device__ __forceinline__ ushort f2bf(float f) {
  uint u = __builtin_bit_cast(uint, f);
  u = (u + 0x7fffu + ((u >> 16) & 1u)) >> 16;  // RNE
  return (ushort)u;
}

// global -> LDS direct DMA, 16B/lane. LDS dest = wave-uniform base + lane*16.
#define GLD16(gp, lp)                                                   \
  __builtin_amdgcn_global_load_lds(                                     \
      (const __attribute__((address_space(1))) uint*)(gp),              \
      (__attribute__((address_space(3))) uint*)(lp), 16, 0, 0)

// ---------------------------------------------------------------------------
// Fused prep: blocks [0,6144): q/k/v fp32 -> bf16 row-major (qb/kb/vb).
//             blocks [6144,6400): WT[z][n][k] = bf16(W[z][k][n]).
// ---------------------------------------------------------------------------
__global__ __launch_bounds__(256) void prep_kernel(
    const float* __restrict__ q, const float* __restrict__ k,
    const float* __restrict__ v, const float* __restrict__ wq,
    const float* __restrict__ wk, const float* __restrict__ wv,
    const float* __restrict__ wo, ushort* __restrict__ qb,
    ushort* __restrict__ kb, ushort* __restrict__ vb,
    ushort* __restrict__ WT) {
  __shared__ float Ws[64][65];
  const int blk = blockIdx.x;
  const int tid = threadIdx.x;
  if (blk < 6144) {
    const int z = blk >> 11, t = blk & 2047;
    const float* src = z == 0 ? q : (z == 1 ? k : v);
    ushort* dst = z == 0 ? qb : (z == 1 ? kb : vb);
    const size_t i8 = ((size_t)t * 256 + tid) * 8;
    const float4 x0 = *(const float4*)(src + i8);
    const float4 x1 = *(const float4*)(src + i8 + 4);
    alignas(16) ushort t8[8] = {f2bf(x0.x), f2bf(x0.y), f2bf(x0.z), f2bf(x0.w),
                                f2bf(x1.x), f2bf(x1.y), f2bf(x1.z), f2bf(x1.w)};
    *(uint4*)(dst + i8) = *(const uint4*)t8;
    return;
  }
  const int w = blk - 6144;  // 0..255
  const int z = w >> 6;
  const float* W = z == 0 ? wq : (z == 1 ? wk : (z == 2 ? wv : wo));
  ushort* T = WT + (size_t)z * kD * kD;
  const int kt = ((w >> 3) & 7) * 64, nt = (w & 7) * 64;
  const int r = tid >> 2, c0 = (tid & 3) * 16;
#pragma unroll
  for (int i = 0; i < 4; ++i) {
    const float4 x =
        *(const float4*)(W + (size_t)(kt + r) * kD + nt + c0 + i * 4);
    Ws[r][c0 + i * 4 + 0] = x.x;
    Ws[r][c0 + i * 4 + 1] = x.y;
    Ws[r][c0 + i * 4 + 2] = x.z;
    Ws[r][c0 + i * 4 + 3] = x.w;
  }
  __syncthreads();
  const int n = tid >> 2, k0 = (tid & 3) * 16;
  alignas(16) ushort tmp[16];
#pragma unroll
  for (int i = 0; i < 16; ++i) tmp[i] = f2bf(Ws[k0 + i][n]);
  ushort* dst = T + (size_t)(nt + n) * kD + kt + k0;
  *(uint4*)(dst + 0) = *(const uint4*)&tmp[0];
  *(uint4*)(dst + 8) = *(const uint4*)&tmp[8];
}

// ---------------------------------------------------------------------------
// TM x 128 BK=32 bf16 MFMA GEMM, 3-stage global_load_lds pipeline, one raw
// s_barrier + vmcnt(loads-per-stage) per iter.
// XCD-aware swizzle: the 4 col-blocks of a row-block share an XCD (x%8) and
// a dispatch window, so the A tile is HBM-fetched once and L2-hit 3x.
// mode = mode_arg + blockIdx.z:
//   0: qb @ WTq + bq -> Qp (bf16 [tok][512])
//   1: kb @ WTk + bk -> Kp (bf16 [tok][512])
//   2: vb @ WTv + bv -> VT (bf16 [bh*64+d][2048], transposed)
//   3: ob @ WTo + bo -> out (fp32 [tok][512])
// ---------------------------------------------------------------------------
template <int TM>
__global__ __launch_bounds__(256) void gemm_kernel(
    const ushort* __restrict__ qb, const ushort* __restrict__ kb,
    const ushort* __restrict__ vb, const ushort* __restrict__ obp,
    const ushort* __restrict__ WT, const float* __restrict__ bq,
    const float* __restrict__ bk, const float* __restrict__ bv,
    const float* __restrict__ bo, ushort* __restrict__ Qp,
    ushort* __restrict__ Kp, ushort* __restrict__ VT,
    float* __restrict__ outp, int mode_arg) {
  const int mode = mode_arg + blockIdx.z;
  const ushort* Ab;
  const float* bias;
  switch (mode) {
    case 0: Ab = qb; bias = bq; break;
    case 1: Ab = kb; bias = bk; break;
    case 2: Ab = vb; bias = bv; break;
    default: Ab = obp; bias = bo; break;
  }
  const ushort* BT = WT + (size_t)mode * kD * kD;

  // A stages: [st * TM*32]; B stages: [3*TM*32 + st*4096] (ushort idx).
  // Rows of 32 bf16 = 4 x 16B chunks; chunk c of row r holds global chunk
  // c ^ s(r), s(r) = (r&3)^((r>>2)&3). No padding (DMA needs contiguity).
  constexpr int A_STAGE = TM * 32;
  constexpr int B_BASE = 3 * A_STAGE;
  constexpr int NI = (TM == 128) ? 4 : 2;
  constexpr int AI = TM / 64;  // A DMA issues per stage (x256 lanes x 16B)
  __shared__ alignas(16) ushort smem[B_BASE + 12288];

  const int tid = threadIdx.x;
  const int wave = tid >> 6, lane = tid & 63, l15 = lane & 15, qd = lane >> 4;
  const int wm = (TM == 128) ? (wave >> 1) * 64 : 0;
  const int wn = (TM == 128) ? (wave & 1) * 64 : wave * 32;
  // XCD-aware swizzle: x%8 = XCD (round-robin dispatch). Same row-block's 4
  // col-blocks get x values 8 apart -> same XCD, consecutive window.
  const int lin = blockIdx.x;
  const int xcd = lin & 7, j = lin >> 3;
  const int rblk = xcd + 8 * (j >> 2), cblk = j & 3;
  const int row0 = rblk * TM, col0 = cblk * 128;
  const int sw = (l15 & 3) ^ (l15 >> 2);  // = s(row) for all frag rows

  const ushort* pA[AI];
  const ushort* pB[2];
  uint ldsA[AI], ldsB[2];
#pragma unroll
  for (int i = 0; i < AI; ++i) {
    const int linear = i * 256 + tid;
    const int r = linear >> 2, c = linear & 3;
    const int g = c ^ ((r & 3) ^ ((r >> 2) & 3));
    pA[i] = Ab + (size_t)(row0 + r) * kD + g * 8;
    ldsA[i] = (uint)(i * 256 + wave * 64) * 8;
  }
#pragma unroll
  for (int i = 0; i < 2; ++i) {
    const int linear = i * 256 + tid;
    const int r = linear >> 2, c = linear & 3;
    const int g = c ^ ((r & 3) ^ ((r >> 2) & 3));
    pB[i] = BT + (size_t)(col0 + r) * kD + g * 8;
    ldsB[i] = (uint)B_BASE + (uint)(i * 256 + wave * 64) * 8;
  }

#define ISSUE(kk, st)                                                     \
  {                                                                       \
    _Pragma("unroll") for (int i = 0; i < AI; ++i)                        \
        GLD16(pA[i] + (kk), &smem[ldsA[i] + (st) * A_STAGE]);             \
    _Pragma("unroll") for (int i = 0; i < 2; ++i)                         \
        GLD16(pB[i] + (kk), &smem[ldsB[i] + (st) * 4096]);                \
  }

  f32x4 acc[4][NI];
#pragma unroll
  for (int mi = 0; mi < 4; ++mi)
#pragma unroll
    for (int ni = 0; ni < NI; ++ni) acc[mi][ni] = (f32x4)(0.f);

  ISSUE(0, 0);
  ISSUE(32, 1);
#pragma unroll
  for (int it = 0; it < 16; ++it) {
    // vmcnt(N) must equal the loads-in-flight for the NEXT stage only:
    // one stage = AI+2 loads. TM=128 -> 4, TM=64 -> 3.
    if (it < 15) {
      if constexpr (TM == 128)
        asm volatile("s_waitcnt vmcnt(4) lgkmcnt(0)\n\ts_barrier" ::: "memory");
      else
        asm volatile("s_waitcnt vmcnt(3) lgkmcnt(0)\n\ts_barrier" ::: "memory");
    } else {
      asm volatile("s_waitcnt vmcnt(0) lgkmcnt(0)\n\ts_barrier" ::: "memory");
    }
    if (it < 14) ISSUE((it + 2) * 32, (it + 2) % 3);
    const ushort* as = &smem[(it % 3) * A_STAGE];
    const ushort* bs = &smem[B_BASE + (it % 3) * 4096];
    bf16x8 af[4], br[NI];
#pragma unroll
    for (int mi = 0; mi < 4; ++mi)
      af[mi] = *(const bf16x8*)&as[(wm + mi * 16 + l15) * 32 + (qd ^ sw) * 8];
#pragma unroll
    for (int ni = 0; ni < NI; ++ni)
      br[ni] = *(const bf16x8*)&bs[(wn + ni * 16 + l15) * 32 + (qd ^ sw) * 8];
#pragma unroll
    for (int mi = 0; mi < 4; ++mi)
#pragma unroll
      for (int ni = 0; ni < NI; ++ni)
        acc[mi][ni] = __builtin_amdgcn_mfma_f32_16x16x32_bf16(
            af[mi], br[ni], acc[mi][ni], 0, 0, 0);
  }
#undef ISSUE

  float bcol[NI];
#pragma unroll
  for (int ni = 0; ni < NI; ++ni) bcol[ni] = bias[col0 + wn + ni * 16 + l15];

  if (mode == 3) {  // fp32 direct stores
#pragma unroll
    for (int mi = 0; mi < 4; ++mi)
#pragma unroll
      for (int ni = 0; ni < NI; ++ni) {
        const int n_g = col0 + wn + ni * 16 + l15;
#pragma unroll
        for (int r = 0; r < 4; ++r) {
          const int token = row0 + wm + mi * 16 + qd * 4 + r;
          outp[(size_t)token * kD + n_g] = acc[mi][ni][r] + bcol[ni];
        }
      }
    return;
  }

  __syncthreads();  // safe to reuse smem for the epilogue transpose

  // bf16 outputs: per-wave 64x64 transpose through LDS (stride 72 ushorts),
  // then 8 x dwordx4 global stores per lane.
  ushort* T = &smem[wave * 4608];
  if (mode <= 1) {  // place [token_local][d_local]
#pragma unroll
    for (int mi = 0; mi < 4; ++mi)
#pragma unroll
      for (int ni = 0; ni < NI; ++ni)
#pragma unroll
        for (int r = 0; r < 4; ++r)
          T[(mi * 16 + qd * 4 + r) * 72 + ni * 16 + l15] =
              f2bf(acc[mi][ni][r] + bcol[ni]);
  } else {  // mode 2: place [d_local][token_local]
#pragma unroll
    for (int mi = 0; mi < 4; ++mi)
#pragma unroll
      for (int ni = 0; ni < NI; ++ni)
#pragma unroll
        for (int r = 0; r < 4; ++r)
          T[(ni * 16 + l15) * 72 + mi * 16 + qd * 4 + r] =
              f2bf(acc[mi][ni][r] + bcol[ni]);
  }
  asm volatile("s_waitcnt lgkmcnt(0)" ::: "memory");  // wave-local visibility

  const ushort* Trow = &smem[wave * 4608 + lane * 72];
  if (mode <= 1) {
    ushort* C = (mode == 0) ? Qp : Kp;
    ushort* dst = C + (size_t)(row0 + wm + lane) * kD + col0 + wn;
#pragma unroll
    for (int c = 0; c < 8; ++c)
      *(uint4*)(dst + c * 8) = *(const uint4*)(Trow + c * 8);
  } else {
    const int n_g = col0 + wn + lane;
    const int h = n_g >> 6, d = n_g & 63;
    const int t0 = row0 + wm;
    const int b = t0 >> 11, ss = t0 & (kS - 1);
    ushort* dst = VT + ((size_t)(b * kH + h) * 64 + d) * kS + ss;
#pragma unroll
    for (int c = 0; c < 8; ++c)
      *(uint4*)(dst + c * 8) = *(const uint4*)(Trow + c * 8);
  }
}

// ---------------------------------------------------------------------------
// MFMA banded attention. One wave per 64-query tile per (b,h). grid (32,32).
// ---------------------------------------------------------------------------
__global__ __launch_bounds__(64, 1) void attn_kernel(
    const ushort* __restrict__ Qp, const ushort* __restrict__ Kp,
    const ushort* __restrict__ VT, ushort* __restrict__ Ob) {
  __shared__ alignas(16) ushort Pl[64 * 104];  // P scatter; reused for O xpose

  const int lane = threadIdx.x, l15 = lane & 15, qd = lane >> 4;
  const int bh = blockIdx.y, b = bh >> 3, h = bh & 7;
  const int q0 = blockIdx.x * 64;
  const int colA = h * 64;

  bf16x8 qf[4][2], kf[6][2];
#pragma unroll
  for (int mi = 0; mi < 4; ++mi) {
    const size_t base =
        ((size_t)b * kS + q0 + mi * 16 + l15) * kD + colA + qd * 8;
#pragma unroll
    for (int kc = 0; kc < 2; ++kc)
      qf[mi][kc] = *(const bf16x8*)&Qp[base + kc * 32];
  }
#pragma unroll
  for (int ni = 0; ni < 6; ++ni) {
    int key = q0 - kBand + ni * 16 + l15;
    key = key < 0 ? 0 : (key > kS - 1 ? kS - 1 : key);  // clamp; masked below
    const size_t base = ((size_t)b * kS + key) * kD + colA + qd * 8;
#pragma unroll
    for (int kc = 0; kc < 2; ++kc)
      kf[ni][kc] = *(const bf16x8*)&Kp[base + kc * 32];
  }

  f32x4 S[4][6];
#pragma unroll
  for (int mi = 0; mi < 4; ++mi)
#pragma unroll
    for (int ni = 0; ni < 6; ++ni) S[mi][ni] = (f32x4)(0.f);
#pragma unroll
  for (int mi = 0; mi < 4; ++mi)
#pragma unroll
    for (int ni = 0; ni < 6; ++ni)
#pragma unroll
      for (int kc = 0; kc < 2; ++kc)
        S[mi][ni] = __builtin_amdgcn_mfma_f32_16x16x32_bf16(
            qf[mi][kc], kf[ni][kc], S[mi][ni], 0, 0, 0);

#pragma unroll
  for (int mi = 0; mi < 4; ++mi)
#pragma unroll
    for (int ni = 0; ni < 6; ++ni)
#pragma unroll
      for (int r = 0; r < 4; ++r) {
        const int q_local = mi * 16 + qd * 4 + r;
        const int key_local = ni * 16 + l15;
        const int key = q0 - kBand + key_local;
        const int dlt = key_local - q_local;
        const bool ok = (dlt >= 0) && (dlt <= 32) && (key >= 0) && (key < kS);
        S[mi][ni][r] = ok ? S[mi][ni][r] * 0.125f : -3.0e38f;
      }

  float inv[4][4];
#pragma unroll
  for (int mi = 0; mi < 4; ++mi)
#pragma unroll
    for (int r = 0; r < 4; ++r) {
      float m = S[mi][0][r];
#pragma unroll
      for (int ni = 1; ni < 6; ++ni) m = fmaxf(m, S[mi][ni][r]);
      m = fmaxf(m, __shfl_xor(m, 1));
      m = fmaxf(m, __shfl_xor(m, 2));
      m = fmaxf(m, __shfl_xor(m, 4));
      m = fmaxf(m, __shfl_xor(m, 8));
      float s = 0.f;
#pragma unroll
      for (int ni = 0; ni < 6; ++ni) {
        const float e = __expf(S[mi][ni][r] - m);
        S[mi][ni][r] = e;
        s += e;
      }
      s += __shfl_xor(s, 1);
      s += __shfl_xor(s, 2);
      s += __shfl_xor(s, 4);
      s += __shfl_xor(s, 8);
      inv[mi][r] = 1.f / s;
    }

  // P -> LDS (C-layout scatter, stride 104), read back in A-layout
#pragma unroll
  for (int mi = 0; mi < 4; ++mi)
#pragma unroll
    for (int ni = 0; ni < 6; ++ni)
#pragma unroll
      for (int r = 0; r < 4; ++r)
        Pl[(mi * 16 + qd * 4 + r) * 104 + ni * 16 + l15] = f2bf(S[mi][ni][r]);
  __syncthreads();

  f32x4 O[4][4];
#pragma unroll
  for (int mi = 0; mi < 4; ++mi)
#pragma unroll
    for (int nt = 0; nt < 4; ++nt) O[mi][nt] = (f32x4)(0.f);

#pragma unroll
  for (int kc = 0; kc < 3; ++kc) {
    bf16x8 pf[4], vfr[4];
#pragma unroll
    for (int mi = 0; mi < 4; ++mi)
      pf[mi] = *(const bf16x8*)&Pl[(mi * 16 + l15) * 104 + kc * 32 + qd * 8];
    int kb0 = q0 - kBand + kc * 32 + qd * 8;
    kb0 = kb0 < 0 ? 0 : (kb0 > kS - 8 ? kS - 8 : kb0);  // clamp; P=0 there
#pragma unroll
    for (int nt = 0; nt < 4; ++nt)
      vfr[nt] =
          *(const bf16x8*)&VT[((size_t)bh * 64 + nt * 16 + l15) * kS + kb0];
#pragma unroll
    for (int mi = 0; mi < 4; ++mi)
#pragma unroll
      for (int nt = 0; nt < 4; ++nt)
        O[mi][nt] = __builtin_amdgcn_mfma_f32_16x16x32_bf16(pf[mi], vfr[nt],
                                                            O[mi][nt], 0, 0, 0);
  }

  // O transpose through LDS (reuse Pl, stride 72), 8 x dwordx4 stores/lane
#pragma unroll
  for (int mi = 0; mi < 4; ++mi)
#pragma unroll
    for (int nt = 0; nt < 4; ++nt)
#pragma unroll
      for (int r = 0; r < 4; ++r)
        Pl[(mi * 16 + qd * 4 + r) * 72 + nt * 16 + l15] =
            f2bf(O[mi][nt][r] * inv[mi][r]);
  asm volatile("s_waitcnt lgkmcnt(0)" ::: "memory");

  ushort* dst = Ob + ((size_t)b * kS + q0 + lane) * kD + colA;
  const ushort* Trow = &Pl[lane * 72];
#pragma unroll
  for (int c = 0; c < 8; ++c)
    *(uint4*)(dst + c * 8) = *(const uint4*)(Trow + c * 8);
}

extern "C" void kernel_launch(void* const* d_in, const int* in_sizes, int n_in,
                              void* d_out, int out_size, void* d_ws,
                              size_t ws_size, hipStream_t stream) {
  const float* q = (const float*)d_in[0];
  const float* k = (const float*)d_in[1];
  const float* v = (const float*)d_in[2];
  const float* wq = (const float*)d_in[3];
  const float* bq = (const float*)d_in[4];
  const float* wk = (const float*)d_in[5];
  const float* bk = (const float*)d_in[6];
  const float* wv = (const float*)d_in[7];
  const float* bv = (const float*)d_in[8];
  const float* wo = (const float*)d_in[9];
  const float* bo = (const float*)d_in[10];
  float* out = (float*)d_out;

  // ws (~58 MB of the ~256 MB available), no aliasing:
  const size_t n1 = (size_t)kNT * kD;  // 4M ushorts = 8 MB
  ushort* qb = (ushort*)d_ws;
  ushort* kb = qb + n1;
  ushort* vb = kb + n1;
  ushort* Qp = vb + n1;
  ushort* Kp = Qp + n1;
  ushort* VT = Kp + n1;
  ushort* Ob = VT + n1;
  ushort* WT = Ob + n1;

  prep_kernel<<<dim3(6400), 256, 0, stream>>>(q, k, v, wq, wk, wv, wo, qb, kb,
                                              vb, WT);
  gemm_kernel<128><<<dim3(256, 1, 3), 256, 0, stream>>>(  // modes 0,1,2
      qb, kb, vb, Ob, WT, bq, bk, bv, bo, Qp, Kp, VT, out, 0);
  attn_kernel<<<dim3(kS / 64, 32), 64, 0, stream>>>(Qp, Kp, VT, Ob);
  gemm_kernel<64><<<dim3(512, 1, 1), 256, 0, stream>>>(  // mode 3
      qb, kb, vb, Ob, WT, bq, bk, bv, bo, Qp, Kp, VT, out, 3);
}